// Round 7
// baseline (4087.866 us; speedup 1.0000x reference)
//
#include <hip/hip_runtime.h>
#include <stdint.h>

#define SC 192      // coarse samples (128 + 64)
#define SF 128      // fine (importance) samples
#define NT 128      // threads per block = 2 waves

typedef float f32x32 __attribute__((ext_vector_type(32)));

// z_log coarse grid: seg0 linspace(-1,-1/128,128) step 1/128; seg1 linspace(0,1-1/64,64) step 1/64
__device__ __forceinline__ float zlog_c(int t) {
  return (t < 128) ? (-1.0f + (float)t * 0.0078125f)
                   : ((float)(t - 128) * 0.015625f);
}
__device__ __forceinline__ float delta_c(int t) {
  if (t >= SC - 1) return 0.0f;
  return zlog_c(t + 1) - zlog_c(t);
}

__device__ __forceinline__ float fast_rcp(float x) { return __builtin_amdgcn_rcpf(x); }
__device__ __forceinline__ float fast_rsq(float x) { return __builtin_amdgcn_rsqf(x); }
__device__ __forceinline__ float exp10_f(float x) { return __expf(x * 2.30258509299f); }

__device__ __forceinline__ float softplus_f(float x) {
  return fmaxf(x, 0.0f) + __logf(1.0f + __expf(-fabsf(x)));
}

// JAX threefry2x32 with key = (0, 42)
__device__ __forceinline__ void threefry2x32_k42(uint32_t& x0, uint32_t& x1) {
  const uint32_t ks0 = 0u, ks1 = 42u;
  const uint32_t ks2 = ks0 ^ ks1 ^ 0x1BD11BDAu;
  const uint32_t ks[3] = {ks0, ks1, ks2};
  const int rot[2][4] = {{13, 15, 26, 6}, {17, 29, 16, 24}};
  x0 += ks[0];
  x1 += ks[1];
#pragma unroll
  for (int i = 0; i < 5; ++i) {
#pragma unroll
    for (int j = 0; j < 4; ++j) {
      x0 += x1;
      const int r = rot[i & 1][j];
      x1 = (x1 << r) | (x1 >> (32 - r));
      x1 ^= x0;
    }
    x0 += ks[(i + 1) % 3];
    x1 += ks[(i + 2) % 3] + (uint32_t)(i + 1);
  }
}

// wave-level inclusive scans (Hillis-Steele via shfl_up, 6 steps)
__device__ __forceinline__ float wave_scan_mul(float v, int lane) {
#pragma unroll
  for (int d = 1; d < 64; d <<= 1) {
    float o = __shfl_up(v, d, 64);
    if (lane >= d) v *= o;
  }
  return v;
}
__device__ __forceinline__ float wave_scan_add(float v, int lane) {
#pragma unroll
  for (int d = 1; d < 64; d <<= 1) {
    float o = __shfl_up(v, d, 64);
    if (lane >= d) v += o;
  }
  return v;
}

// density MLP, sigma only (coarse) — weights from LDS (broadcast ds_read,
// constant offsets; no per-weight address VALU, no VMEM in the loop)
__device__ __forceinline__ float density_sigma_lds(
    float px, float py, float pz,
    const float* wd1, const float* bd1v, const float* wd2, float bd2v) {
  float acc = bd2v;
#pragma unroll
  for (int k = 0; k < 32; ++k) {
    float v = bd1v[k] + px * wd1[k] + py * wd1[32 + k] + pz * wd1[64 + k];
    acc += fmaxf(v, 0.0f) * wd2[k];
  }
  return softplus_f(acc);
}

// NOTE: no min-waves arg in __launch_bounds__ — a (128,4) bound caps the
// unified VGPR+AGPR budget at 128 and pushed MLP arrays into AGPRs (r4/r5).
__global__ __launch_bounds__(NT) void nerf_fwd(
    const float* __restrict__ hh, const float* __restrict__ ww,
    const float* __restrict__ K, const float* __restrict__ E,
    const float* __restrict__ bg,
    const float* __restrict__ Wd1, const float* __restrict__ bd1,
    const float* __restrict__ Wd2, const float* __restrict__ bd2,
    const float* __restrict__ Wc1, const float* __restrict__ bc1,
    const float* __restrict__ Wc2, const float* __restrict__ bc2,
    float* __restrict__ out, int n_rays) {
  const int ray = blockIdx.x;
  const int t = threadIdx.x;
  const int lane = t & 63;
  const int wv = t >> 6;   // 0 or 1

  // weight table in LDS (f32): [Wd1 96][bd1 32][Wd2 32][bd2 1][pad 3][Wc1 1120][bc1 32][Wc2 96][bc2 3]
  __shared__ float sw[96 + 32 + 32 + 4 + 1120 + 32 + 96 + 4];
  float* const l_wd1 = sw;            // 96
  float* const l_bd1 = sw + 96;       // 32
  float* const l_wd2 = sw + 128;      // 32
  float* const l_bd2 = sw + 160;      // 1 (+3 pad -> Wc1 16B-aligned)
  float* const l_wc1 = sw + 164;      // 1120
  float* const l_bc1 = sw + 1284;     // 32
  float* const l_wc2 = sw + 1316;     // 96
  float* const l_bc2 = sw + 1412;     // 3

  __shared__ float s_w[SC];     // coarse weights
  __shared__ float s_cdf[SC];   // coarse CDF
  __shared__ float s_zlf[SF];   // fine z_log
  __shared__ float s_tot[8];    // chunk totals
  __shared__ float s_red[16];   // 2 waves x 5 partial sums

  // ---- stage all weights into LDS (coalesced, once per block) ----
  for (int i = t; i < 96; i += NT)   l_wd1[i] = Wd1[i];
  for (int i = t; i < 32; i += NT) { l_bd1[i] = bd1[i]; l_wd2[i] = Wd2[i]; l_bc1[i] = bc1[i]; }
  if (t == 0) l_bd2[0] = bd2[0];
  for (int i = t; i < 1120; i += NT) l_wc1[i] = Wc1[i];
  for (int i = t; i < 96; i += NT)   l_wc2[i] = Wc2[i];
  for (int i = t; i < 3; i += NT)    l_bc2[i] = bc2[i];

  // ---- ray setup (block-uniform; overlaps the staging loads) ----
  const float k00 = K[0], k01 = K[1], k02 = K[2];
  const float k10 = K[3], k11 = K[4], k12 = K[5];
  const float k20 = K[6], k21 = K[7], k22 = K[8];
  const float det = k00 * (k11 * k22 - k12 * k21)
                  - k01 * (k10 * k22 - k12 * k20)
                  + k02 * (k10 * k21 - k11 * k20);
  const float id = 1.0f / det;
  const float i00 =  (k11 * k22 - k12 * k21) * id;
  const float i01 = -(k01 * k22 - k02 * k21) * id;
  const float i02 =  (k01 * k12 - k02 * k11) * id;
  const float i10 = -(k10 * k22 - k12 * k20) * id;
  const float i11 =  (k00 * k22 - k02 * k20) * id;
  const float i12 = -(k00 * k12 - k02 * k10) * id;
  const float i20 =  (k10 * k21 - k11 * k20) * id;
  const float i21 = -(k00 * k21 - k01 * k20) * id;
  const float i22 =  (k00 * k11 - k01 * k10) * id;

  const float dwx = ww[ray] + 0.5f;
  const float dwy = hh[ray] + 0.5f;
  const float cx = i00 * dwx + i01 * dwy + i02;
  const float cy = i10 * dwx + i11 * dwy + i12;
  const float cz = i20 * dwx + i21 * dwy + i22;
  const float* Er = E + (size_t)ray * 16;
  const float ox = Er[3], oy = Er[7], oz = Er[11];
  const float dx = Er[0] * cx + Er[1] * cy + Er[2] * cz;
  const float dy = Er[4] * cx + Er[5] * cy + Er[6] * cz;
  const float dz = Er[8] * cx + Er[9] * cy + Er[10] * cz;
  const float inv_nrm = fast_rsq(dx * dx + dy * dy + dz * dz);
  const float ndx = dx * inv_nrm, ndy = dy * inv_nrm, ndz = dz * inv_nrm;

  __syncthreads();   // weights staged

  // ---- coarse pass: e0 = t (all threads); e1 = 128+t (wave 0 only) ----
  const float l_bd2v = l_bd2[0];
  float a0, v0, a1e = 0.0f, v1e = 1.0f;
  {
    const float z = exp10_f(zlog_c(t));
    float px = ox + dx * z, py = oy + dy * z, pz = oz + dz * z;
    const float dist = sqrtf(px * px + py * py + pz * pz);
    if (dist > 1.0f) {
      const float invd = fast_rcp(dist);
      const float sc = (2.0f - invd) * invd;
      px *= sc; py *= sc; pz *= sc;
    }
    const float sig = density_sigma_lds(px, py, pz, l_wd1, l_bd1, l_wd2, l_bd2v);
    v0 = __expf(-sig * delta_c(t));   // 1 - alpha
    a0 = 1.0f - v0;
  }
  if (wv == 0) {
    const int e = 128 + t;
    const float z = exp10_f(zlog_c(e));
    float px = ox + dx * z, py = oy + dy * z, pz = oz + dz * z;
    const float dist = sqrtf(px * px + py * py + pz * pz);
    if (dist > 1.0f) {
      const float invd = fast_rcp(dist);
      const float sc = (2.0f - invd) * invd;
      px *= sc; py *= sc; pz *= sc;
    }
    const float sig = density_sigma_lds(px, py, pz, l_wd1, l_bd1, l_wd2, l_bd2v);
    v1e = __expf(-sig * delta_c(e));
    a1e = 1.0f - v1e;
  }

  // parallel cumprod of (1-alpha)
  float i0 = wave_scan_mul(v0, lane);
  float i1 = 1.0f;
  if (wv == 0) i1 = wave_scan_mul(v1e, lane);
  if (lane == 63) s_tot[wv] = i0;
  if (wv == 0 && lane == 63) s_tot[2] = i1;
  __syncthreads();
  {
    const float preC1 = s_tot[0];
    const float preC2 = s_tot[0] * s_tot[1];
    float e0x = __shfl_up(i0, 1, 64); if (lane == 0) e0x = 1.0f;
    s_w[t] = a0 * e0x * (wv ? preC1 : 1.0f);
    if (wv == 0) {
      float e1x = __shfl_up(i1, 1, 64); if (lane == 0) e1x = 1.0f;
      s_w[128 + t] = a1e * e1x * preC2;
    }
  }
  __syncthreads();

  // reweight
  float wre0, wre1 = 0.0f;
  {
    const float wm = (t > 0) ? s_w[t - 1] : 0.0f;
    const float w0 = s_w[t];
    const float wp = s_w[t + 1];
    wre0 = 0.5f * (fmaxf(wm, w0) + fmaxf(w0, wp)) + (0.02f / 192.0f);
    wre0 *= (t < 128) ? (128.0f / 192.0f) : (64.0f / 192.0f);
  }
  if (wv == 0) {
    const int e = 128 + t;
    const float wm = s_w[e - 1];
    const float w0 = s_w[e];
    const float wp = (e < SC - 1) ? s_w[e + 1] : 0.0f;
    wre1 = 0.5f * (fmaxf(wm, w0) + fmaxf(w0, wp)) + (0.02f / 192.0f);
    wre1 *= (64.0f / 192.0f);
  }

  // parallel cumsum -> normalized CDF
  float s0 = wave_scan_add(wre0, lane);
  float s1 = 0.0f;
  if (wv == 0) s1 = wave_scan_add(wre1, lane);
  if (lane == 63) s_tot[4 + wv] = s0;
  if (wv == 0 && lane == 63) s_tot[6] = s1;
  __syncthreads();
  {
    const float T0 = s_tot[4], T1 = s_tot[5], T2 = s_tot[6];
    const float inv_total = fast_rcp(T0 + T1 + T2);
    s_cdf[t] = (s0 + (wv ? T0 : 0.0f)) * inv_total;
    if (wv == 0) s_cdf[128 + t] = (s1 + T0 + T1) * inv_total;
  }
  __syncthreads();

  // ---- importance sampling (ALL 128 threads) ----
  float zlf, zf;
  {
    const uint32_t total = (uint32_t)n_rays * 128u;
    const uint32_t halfc = total >> 1;
    const uint32_t j = (uint32_t)ray * 128u + (uint32_t)t;
    uint32_t x0, x1;
    const bool first = (j < halfc);
    if (first) { x0 = j; x1 = j + halfc; } else { x0 = j - halfc; x1 = j; }
    threefry2x32_k42(x0, x1);
    const uint32_t bits = first ? x0 : x1;
    const float fr = __uint_as_float((bits >> 9) | 0x3f800000u) - 1.0f;

    float u = (float)t * 0.0078125f + fr * 0.0078125f;
    u = u * (s_cdf[190] - s_cdf[1]) + s_cdf[1];

    // searchsorted(cdf[1:190], u, side='right') + 1
    int lo = 0, hi = 189;
    while (lo < hi) {
      const int mid = (lo + hi) >> 1;
      if (s_cdf[1 + mid] <= u) lo = mid + 1; else hi = mid;
    }
    const int inds = lo + 1;  // [1, 190]
    const float cb = s_cdf[inds - 1], ca = s_cdf[inds];
    const float tt = (u - cb) * fast_rcp(ca - cb);
    const float zb = 0.5f * (zlog_c(inds - 1) + zlog_c(inds));
    const float za = 0.5f * (zlog_c(inds) + zlog_c(inds + 1));
    zlf = zb + (za - zb) * tt;
    s_zlf[t] = zlf;
    zf = exp10_f(zlf);
  }
  __syncthreads();

  // ---- fine pass: density + color layer-1 fused; all weights from LDS ----
  float cr, cg, cbl, sigf;
  {
    float px = ox + dx * zf, py = oy + dy * zf, pz = oz + dz * zf;
    const float dist = sqrtf(px * px + py * py + pz * pz);
    if (dist > 1.0f) {
      const float invd = fast_rcp(dist);
      const float sc = (2.0f - invd) * invd;
      px *= sc; py *= sc; pz *= sc;
    }

    f32x32 a1;
#pragma unroll
    for (int k = 0; k < 32; ++k)
      a1[k] = l_bc1[k] + ndx * l_wc1[32 * 32 + k]
                       + ndy * l_wc1[33 * 32 + k]
                       + ndz * l_wc1[34 * 32 + k];

    float sig_acc = l_bd2v;
#pragma unroll
    for (int i = 0; i < 32; ++i) {
      float hv = l_bd1[i] + px * l_wd1[i] + py * l_wd1[32 + i] + pz * l_wd1[64 + i];
      hv = fmaxf(hv, 0.0f);
      sig_acc += hv * l_wd2[i];
#pragma unroll
      for (int k = 0; k < 32; ++k) a1[k] += hv * l_wc1[i * 32 + k];
    }
    sigf = softplus_f(sig_acc);

    float o0 = l_bc2[0], o1 = l_bc2[1], o2 = l_bc2[2];
#pragma unroll
    for (int k = 0; k < 32; ++k) {
      const float av = fmaxf(a1[k], 0.0f);
      o0 += av * l_wc2[k * 3 + 0];
      o1 += av * l_wc2[k * 3 + 1];
      o2 += av * l_wc2[k * 3 + 2];
    }
    cr  = fast_rcp(1.0f + __expf(-o0));
    cg  = fast_rcp(1.0f + __expf(-o1));
    cbl = fast_rcp(1.0f + __expf(-o2));
  }

  // fine alpha + parallel cumprod over 128 (2 chunks of 64)
  const float deltaf = (t < SF - 1) ? (s_zlf[t + 1] - zlf) : 0.0f;
  const float vf = __expf(-sigf * deltaf);
  const float af = 1.0f - vf;
  float fi = wave_scan_mul(vf, lane);
  if (lane == 63) s_tot[wv] = fi;
  __syncthreads();
  float efx = __shfl_up(fi, 1, 64); if (lane == 0) efx = 1.0f;
  const float wf = af * efx * (wv ? s_tot[0] : 1.0f);

  // ---- outputs ----
  float* o_img = out;
  float* o_w   = out + (size_t)n_rays * 3;
  float* o_z   = out + (size_t)n_rays * (3 + 128);
  float* o_inv = out + (size_t)n_rays * (3 + 256);

  o_w[(size_t)ray * 128 + t] = wf;
  o_z[(size_t)ray * 128 + t] = (zlf + 1.0f) * 0.5f;

  // reductions: image rgb, acc weight, invdepth
  float r0 = wf * cr, r1 = wf * cg, r2 = wf * cbl, r3 = wf, r4 = wf * fast_rcp(zf);
#pragma unroll
  for (int d = 32; d > 0; d >>= 1) {
    r0 += __shfl_down(r0, d, 64);
    r1 += __shfl_down(r1, d, 64);
    r2 += __shfl_down(r2, d, 64);
    r3 += __shfl_down(r3, d, 64);
    r4 += __shfl_down(r4, d, 64);
  }
  if (lane == 0) {
    float* p = &s_red[wv * 5];
    p[0] = r0; p[1] = r1; p[2] = r2; p[3] = r3; p[4] = r4;
  }
  __syncthreads();
  if (t == 0) {
    const float accw = s_red[3] + s_red[8];
    const float bgw = 1.0f - accw;
    o_img[(size_t)ray * 3 + 0] = (s_red[0] + s_red[5]) + bgw * bg[0];
    o_img[(size_t)ray * 3 + 1] = (s_red[1] + s_red[6]) + bgw * bg[1];
    o_img[(size_t)ray * 3 + 2] = (s_red[2] + s_red[7]) + bgw * bg[2];
    o_inv[ray] = s_red[4] + s_red[9];
  }
}

extern "C" void kernel_launch(void* const* d_in, const int* in_sizes, int n_in,
                              void* d_out, int out_size, void* d_ws, size_t ws_size,
                              hipStream_t stream) {
  // setup_inputs order: n, h, w, K, E, bg_color, Wd1, bd1, Wd2, bd2, Wc1, bc1, Wc2, bc2
  const float* h   = (const float*)d_in[1];
  const float* w   = (const float*)d_in[2];
  const float* K   = (const float*)d_in[3];
  const float* E   = (const float*)d_in[4];
  const float* bg  = (const float*)d_in[5];
  const float* Wd1 = (const float*)d_in[6];
  const float* bd1 = (const float*)d_in[7];
  const float* Wd2 = (const float*)d_in[8];
  const float* bd2 = (const float*)d_in[9];
  const float* Wc1 = (const float*)d_in[10];
  const float* bc1 = (const float*)d_in[11];
  const float* Wc2 = (const float*)d_in[12];
  const float* bc2 = (const float*)d_in[13];
  const int n_rays = in_sizes[1];

  nerf_fwd<<<n_rays, NT, 0, stream>>>(h, w, K, E, bg, Wd1, bd1, Wd2, bd2,
                                      Wc1, bc1, Wc2, bc2,
                                      (float*)d_out, n_rays);
}

// Round 8
// 245.489 us; speedup vs baseline: 16.6519x; 16.6519x over previous
//
#include <hip/hip_runtime.h>
#include <stdint.h>

#define SC 192      // coarse samples (128 + 64)
#define SF 128      // fine (importance) samples
#define NT 128      // threads per block = 2 waves

// LDS weight-table offsets (floats)
#define WD1  0      // 96  (3x32 row-major)
#define BD1  96     // 32
#define WD2  128    // 32
#define BD2  160    // 1 (+3 pad)
#define WC1  164    // 1120 (35x32 row-major), 16B-aligned
#define BC1  1284   // 32
#define WC2  1316   // 96 (32x3)
#define BC2  1412   // 3 (+1 pad)
#define HPK  1416   // 32x8 packed per-hidden: [Wd1r0,Wd1r1,Wd1r2,bd1, Wd2,pad,pad,pad]
#define SWTOT (1416 + 256)

// z_log coarse grid: seg0 linspace(-1,-1/128,128) step 1/128; seg1 linspace(0,1-1/64,64) step 1/64
__device__ __forceinline__ float zlog_c(int t) {
  return (t < 128) ? (-1.0f + (float)t * 0.0078125f)
                   : ((float)(t - 128) * 0.015625f);
}
__device__ __forceinline__ float delta_c(int t) {
  if (t >= SC - 1) return 0.0f;
  return zlog_c(t + 1) - zlog_c(t);
}

__device__ __forceinline__ float fast_rcp(float x) { return __builtin_amdgcn_rcpf(x); }
__device__ __forceinline__ float fast_rsq(float x) { return __builtin_amdgcn_rsqf(x); }
__device__ __forceinline__ float exp10_f(float x) { return __expf(x * 2.30258509299f); }

__device__ __forceinline__ float softplus_f(float x) {
  return fmaxf(x, 0.0f) + __logf(1.0f + __expf(-fabsf(x)));
}

__device__ __forceinline__ float4 ldsf4(const float* p) {
  return *(const float4*)p;
}

// JAX threefry2x32 with key = (0, 42)
__device__ __forceinline__ void threefry2x32_k42(uint32_t& x0, uint32_t& x1) {
  const uint32_t ks0 = 0u, ks1 = 42u;
  const uint32_t ks2 = ks0 ^ ks1 ^ 0x1BD11BDAu;
  const uint32_t ks[3] = {ks0, ks1, ks2};
  const int rot[2][4] = {{13, 15, 26, 6}, {17, 29, 16, 24}};
  x0 += ks[0];
  x1 += ks[1];
#pragma unroll
  for (int i = 0; i < 5; ++i) {
#pragma unroll
    for (int j = 0; j < 4; ++j) {
      x0 += x1;
      const int r = rot[i & 1][j];
      x1 = (x1 << r) | (x1 >> (32 - r));
      x1 ^= x0;
    }
    x0 += ks[(i + 1) % 3];
    x1 += ks[(i + 2) % 3] + (uint32_t)(i + 1);
  }
}

// wave-level inclusive scans (Hillis-Steele via shfl_up, 6 steps)
__device__ __forceinline__ float wave_scan_mul(float v, int lane) {
#pragma unroll
  for (int d = 1; d < 64; d <<= 1) {
    float o = __shfl_up(v, d, 64);
    if (lane >= d) v *= o;
  }
  return v;
}
__device__ __forceinline__ float wave_scan_add(float v, int lane) {
#pragma unroll
  for (int d = 1; d < 64; d <<= 1) {
    float o = __shfl_up(v, d, 64);
    if (lane >= d) v += o;
  }
  return v;
}

// coarse density: float4 LDS reads, unroll kept at 1 to bound live ranges.
// Accumulation order identical to the scalar k=0..31 loop.
__device__ __forceinline__ float density_sigma_lds(
    float px, float py, float pz, const float* sw, float bd2v) {
  float acc = bd2v;
#pragma unroll 1
  for (int c = 0; c < 8; ++c) {
    const int k4 = c * 4;
    const float4 w0 = ldsf4(sw + WD1 + k4);
    const float4 w1 = ldsf4(sw + WD1 + 32 + k4);
    const float4 w2 = ldsf4(sw + WD1 + 64 + k4);
    const float4 b  = ldsf4(sw + BD1 + k4);
    const float4 wd = ldsf4(sw + WD2 + k4);
    float v;
    v = b.x + px * w0.x + py * w1.x + pz * w2.x; acc += fmaxf(v, 0.0f) * wd.x;
    v = b.y + px * w0.y + py * w1.y + pz * w2.y; acc += fmaxf(v, 0.0f) * wd.y;
    v = b.z + px * w0.z + py * w1.z + pz * w2.z; acc += fmaxf(v, 0.0f) * wd.z;
    v = b.w + px * w0.w + py * w1.w + pz * w2.w; acc += fmaxf(v, 0.0f) * wd.w;
  }
  return softplus_f(acc);
}

// no min-waves arg: a (128,4) bound caps unified VGPR budget at 128 (r4/r5 AGPR trap)
__global__ __launch_bounds__(NT) void nerf_fwd(
    const float* __restrict__ hh, const float* __restrict__ ww,
    const float* __restrict__ K, const float* __restrict__ E,
    const float* __restrict__ bg,
    const float* __restrict__ Wd1, const float* __restrict__ bd1,
    const float* __restrict__ Wd2, const float* __restrict__ bd2,
    const float* __restrict__ Wc1, const float* __restrict__ bc1,
    const float* __restrict__ Wc2, const float* __restrict__ bc2,
    float* __restrict__ out, int n_rays) {
  const int ray = blockIdx.x;
  const int t = threadIdx.x;
  const int lane = t & 63;
  const int wv = t >> 6;   // 0 or 1

  __shared__ float sw[SWTOT];
  __shared__ float s_w[SC];     // coarse weights
  __shared__ float s_cdf[SC];   // coarse CDF
  __shared__ float s_zlf[SF];   // fine z_log
  __shared__ float s_tot[8];    // chunk totals
  __shared__ float s_red[16];   // 2 waves x 5 partial sums

  // ---- stage all weights into LDS (coalesced, once per block) ----
  for (int i = t; i < 96; i += NT)   sw[WD1 + i] = Wd1[i];
  for (int i = t; i < 32; i += NT) { sw[BD1 + i] = bd1[i]; sw[WD2 + i] = Wd2[i]; sw[BC1 + i] = bc1[i]; }
  if (t == 0) sw[BD2] = bd2[0];
  for (int i = t; i < 1120; i += NT) sw[WC1 + i] = Wc1[i];
  for (int i = t; i < 96; i += NT)   sw[WC2 + i] = Wc2[i];
  for (int i = t; i < 3; i += NT)    sw[BC2 + i] = bc2[i];
  if (t < 32) {  // packed per-hidden table for the fine fused loop
    sw[HPK + t * 8 + 0] = Wd1[t];
    sw[HPK + t * 8 + 1] = Wd1[32 + t];
    sw[HPK + t * 8 + 2] = Wd1[64 + t];
    sw[HPK + t * 8 + 3] = bd1[t];
    sw[HPK + t * 8 + 4] = Wd2[t];
  }

  // ---- ray setup (block-uniform; overlaps staging) ----
  const float k00 = K[0], k01 = K[1], k02 = K[2];
  const float k10 = K[3], k11 = K[4], k12 = K[5];
  const float k20 = K[6], k21 = K[7], k22 = K[8];
  const float det = k00 * (k11 * k22 - k12 * k21)
                  - k01 * (k10 * k22 - k12 * k20)
                  + k02 * (k10 * k21 - k11 * k20);
  const float id = 1.0f / det;
  const float i00 =  (k11 * k22 - k12 * k21) * id;
  const float i01 = -(k01 * k22 - k02 * k21) * id;
  const float i02 =  (k01 * k12 - k02 * k11) * id;
  const float i10 = -(k10 * k22 - k12 * k20) * id;
  const float i11 =  (k00 * k22 - k02 * k20) * id;
  const float i12 = -(k00 * k12 - k02 * k10) * id;
  const float i20 =  (k10 * k21 - k11 * k20) * id;
  const float i21 = -(k00 * k21 - k01 * k20) * id;
  const float i22 =  (k00 * k11 - k01 * k10) * id;

  const float dwx = ww[ray] + 0.5f;
  const float dwy = hh[ray] + 0.5f;
  const float cx = i00 * dwx + i01 * dwy + i02;
  const float cy = i10 * dwx + i11 * dwy + i12;
  const float cz = i20 * dwx + i21 * dwy + i22;
  const float* Er = E + (size_t)ray * 16;
  const float ox = Er[3], oy = Er[7], oz = Er[11];
  const float dx = Er[0] * cx + Er[1] * cy + Er[2] * cz;
  const float dy = Er[4] * cx + Er[5] * cy + Er[6] * cz;
  const float dz = Er[8] * cx + Er[9] * cy + Er[10] * cz;
  const float inv_nrm = fast_rsq(dx * dx + dy * dy + dz * dz);
  const float ndx = dx * inv_nrm, ndy = dy * inv_nrm, ndz = dz * inv_nrm;

  __syncthreads();   // weights staged

  // ---- coarse pass: e0 = t (all threads); e1 = 128+t (wave 0 only) ----
  const float bd2v = sw[BD2];
  float a0, v0, a1e = 0.0f, v1e = 1.0f;
  {
    const float z = exp10_f(zlog_c(t));
    float px = ox + dx * z, py = oy + dy * z, pz = oz + dz * z;
    const float dist = sqrtf(px * px + py * py + pz * pz);
    if (dist > 1.0f) {
      const float invd = fast_rcp(dist);
      const float sc = (2.0f - invd) * invd;
      px *= sc; py *= sc; pz *= sc;
    }
    const float sig = density_sigma_lds(px, py, pz, sw, bd2v);
    v0 = __expf(-sig * delta_c(t));   // 1 - alpha
    a0 = 1.0f - v0;
  }
  if (wv == 0) {
    const int e = 128 + t;
    const float z = exp10_f(zlog_c(e));
    float px = ox + dx * z, py = oy + dy * z, pz = oz + dz * z;
    const float dist = sqrtf(px * px + py * py + pz * pz);
    if (dist > 1.0f) {
      const float invd = fast_rcp(dist);
      const float sc = (2.0f - invd) * invd;
      px *= sc; py *= sc; pz *= sc;
    }
    const float sig = density_sigma_lds(px, py, pz, sw, bd2v);
    v1e = __expf(-sig * delta_c(e));
    a1e = 1.0f - v1e;
  }

  // parallel cumprod of (1-alpha)
  float i0 = wave_scan_mul(v0, lane);
  float i1 = 1.0f;
  if (wv == 0) i1 = wave_scan_mul(v1e, lane);
  if (lane == 63) s_tot[wv] = i0;
  if (wv == 0 && lane == 63) s_tot[2] = i1;
  __syncthreads();
  {
    const float preC1 = s_tot[0];
    const float preC2 = s_tot[0] * s_tot[1];
    float e0x = __shfl_up(i0, 1, 64); if (lane == 0) e0x = 1.0f;
    s_w[t] = a0 * e0x * (wv ? preC1 : 1.0f);
    if (wv == 0) {
      float e1x = __shfl_up(i1, 1, 64); if (lane == 0) e1x = 1.0f;
      s_w[128 + t] = a1e * e1x * preC2;
    }
  }
  __syncthreads();

  // reweight
  float wre0, wre1 = 0.0f;
  {
    const float wm = (t > 0) ? s_w[t - 1] : 0.0f;
    const float w0 = s_w[t];
    const float wp = s_w[t + 1];
    wre0 = 0.5f * (fmaxf(wm, w0) + fmaxf(w0, wp)) + (0.02f / 192.0f);
    wre0 *= (t < 128) ? (128.0f / 192.0f) : (64.0f / 192.0f);
  }
  if (wv == 0) {
    const int e = 128 + t;
    const float wm = s_w[e - 1];
    const float w0 = s_w[e];
    const float wp = (e < SC - 1) ? s_w[e + 1] : 0.0f;
    wre1 = 0.5f * (fmaxf(wm, w0) + fmaxf(w0, wp)) + (0.02f / 192.0f);
    wre1 *= (64.0f / 192.0f);
  }

  // parallel cumsum -> normalized CDF
  float s0 = wave_scan_add(wre0, lane);
  float s1 = 0.0f;
  if (wv == 0) s1 = wave_scan_add(wre1, lane);
  if (lane == 63) s_tot[4 + wv] = s0;
  if (wv == 0 && lane == 63) s_tot[6] = s1;
  __syncthreads();
  {
    const float T0 = s_tot[4], T1 = s_tot[5], T2 = s_tot[6];
    const float inv_total = fast_rcp(T0 + T1 + T2);
    s_cdf[t] = (s0 + (wv ? T0 : 0.0f)) * inv_total;
    if (wv == 0) s_cdf[128 + t] = (s1 + T0 + T1) * inv_total;
  }
  __syncthreads();

  // ---- importance sampling (ALL 128 threads) ----
  float zlf, zf;
  {
    const uint32_t total = (uint32_t)n_rays * 128u;
    const uint32_t halfc = total >> 1;
    const uint32_t j = (uint32_t)ray * 128u + (uint32_t)t;
    uint32_t x0, x1;
    const bool first = (j < halfc);
    if (first) { x0 = j; x1 = j + halfc; } else { x0 = j - halfc; x1 = j; }
    threefry2x32_k42(x0, x1);
    const uint32_t bits = first ? x0 : x1;
    const float fr = __uint_as_float((bits >> 9) | 0x3f800000u) - 1.0f;

    float u = (float)t * 0.0078125f + fr * 0.0078125f;
    u = u * (s_cdf[190] - s_cdf[1]) + s_cdf[1];

    // searchsorted(cdf[1:190], u, side='right') + 1
    int lo = 0, hi = 189;
    while (lo < hi) {
      const int mid = (lo + hi) >> 1;
      if (s_cdf[1 + mid] <= u) lo = mid + 1; else hi = mid;
    }
    const int inds = lo + 1;  // [1, 190]
    const float cb = s_cdf[inds - 1], ca = s_cdf[inds];
    const float tt = (u - cb) * fast_rcp(ca - cb);
    const float zb = 0.5f * (zlog_c(inds - 1) + zlog_c(inds));
    const float za = 0.5f * (zlog_c(inds) + zlog_c(inds + 1));
    zlf = zb + (za - zb) * tt;
    s_zlf[t] = zlf;
    zf = exp10_f(zlf);
  }
  __syncthreads();

  // ---- fine pass: density + color layer-1 fused; unroll-2 i-loop, float4 LDS reads ----
  float cr, cg, cbl, sigf;
  {
    float px = ox + dx * zf, py = oy + dy * zf, pz = oz + dz * zf;
    const float dist = sqrtf(px * px + py * py + pz * pz);
    if (dist > 1.0f) {
      const float invd = fast_rcp(dist);
      const float sc = (2.0f - invd) * invd;
      px *= sc; py *= sc; pz *= sc;
    }

    float4 a1[8];
#pragma unroll
    for (int c = 0; c < 8; ++c) {
      const int k4 = c * 4;
      const float4 b  = ldsf4(sw + BC1 + k4);
      const float4 wx = ldsf4(sw + WC1 + 32 * 32 + k4);
      const float4 wy = ldsf4(sw + WC1 + 33 * 32 + k4);
      const float4 wz = ldsf4(sw + WC1 + 34 * 32 + k4);
      a1[c].x = b.x + ndx * wx.x + ndy * wy.x + ndz * wz.x;
      a1[c].y = b.y + ndx * wx.y + ndy * wy.y + ndz * wz.y;
      a1[c].z = b.z + ndx * wx.z + ndy * wy.z + ndz * wz.z;
      a1[c].w = b.w + ndx * wx.w + ndy * wy.w + ndz * wz.w;
    }

    float sig_acc = bd2v;
#pragma unroll 2
    for (int i = 0; i < 32; ++i) {
      const float4 hp = ldsf4(sw + HPK + i * 8);   // Wd1r0, Wd1r1, Wd1r2, bd1
      const float wd2i = sw[HPK + i * 8 + 4];
      float hv = hp.w + px * hp.x + py * hp.y + pz * hp.z;
      hv = fmaxf(hv, 0.0f);
      sig_acc += hv * wd2i;
      const float* wrow = sw + WC1 + i * 32;
#pragma unroll
      for (int c = 0; c < 8; ++c) {
        const float4 w = ldsf4(wrow + c * 4);
        a1[c].x += hv * w.x;
        a1[c].y += hv * w.y;
        a1[c].z += hv * w.z;
        a1[c].w += hv * w.w;
      }
    }
    sigf = softplus_f(sig_acc);

    float o0 = sw[BC2 + 0], o1 = sw[BC2 + 1], o2 = sw[BC2 + 2];
#pragma unroll
    for (int c = 0; c < 8; ++c) {
      const int k4 = c * 4;
#pragma unroll
      for (int q = 0; q < 4; ++q) {
        const float av = fmaxf(((const float*)&a1[c])[q], 0.0f);
        const int k = k4 + q;
        o0 += av * sw[WC2 + k * 3 + 0];
        o1 += av * sw[WC2 + k * 3 + 1];
        o2 += av * sw[WC2 + k * 3 + 2];
      }
    }
    cr  = fast_rcp(1.0f + __expf(-o0));
    cg  = fast_rcp(1.0f + __expf(-o1));
    cbl = fast_rcp(1.0f + __expf(-o2));
  }

  // fine alpha + parallel cumprod over 128 (2 chunks of 64)
  const float deltaf = (t < SF - 1) ? (s_zlf[t + 1] - zlf) : 0.0f;
  const float vf = __expf(-sigf * deltaf);
  const float af = 1.0f - vf;
  float fi = wave_scan_mul(vf, lane);
  if (lane == 63) s_tot[wv] = fi;
  __syncthreads();
  float efx = __shfl_up(fi, 1, 64); if (lane == 0) efx = 1.0f;
  const float wf = af * efx * (wv ? s_tot[0] : 1.0f);

  // ---- outputs ----
  float* o_img = out;
  float* o_w   = out + (size_t)n_rays * 3;
  float* o_z   = out + (size_t)n_rays * (3 + 128);
  float* o_inv = out + (size_t)n_rays * (3 + 256);

  o_w[(size_t)ray * 128 + t] = wf;
  o_z[(size_t)ray * 128 + t] = (zlf + 1.0f) * 0.5f;

  // reductions: image rgb, acc weight, invdepth
  float r0 = wf * cr, r1 = wf * cg, r2 = wf * cbl, r3 = wf, r4 = wf * fast_rcp(zf);
#pragma unroll
  for (int d = 32; d > 0; d >>= 1) {
    r0 += __shfl_down(r0, d, 64);
    r1 += __shfl_down(r1, d, 64);
    r2 += __shfl_down(r2, d, 64);
    r3 += __shfl_down(r3, d, 64);
    r4 += __shfl_down(r4, d, 64);
  }
  if (lane == 0) {
    float* p = &s_red[wv * 5];
    p[0] = r0; p[1] = r1; p[2] = r2; p[3] = r3; p[4] = r4;
  }
  __syncthreads();
  if (t == 0) {
    const float accw = s_red[3] + s_red[8];
    const float bgw = 1.0f - accw;
    o_img[(size_t)ray * 3 + 0] = (s_red[0] + s_red[5]) + bgw * bg[0];
    o_img[(size_t)ray * 3 + 1] = (s_red[1] + s_red[6]) + bgw * bg[1];
    o_img[(size_t)ray * 3 + 2] = (s_red[2] + s_red[7]) + bgw * bg[2];
    o_inv[ray] = s_red[4] + s_red[9];
  }
}

extern "C" void kernel_launch(void* const* d_in, const int* in_sizes, int n_in,
                              void* d_out, int out_size, void* d_ws, size_t ws_size,
                              hipStream_t stream) {
  // setup_inputs order: n, h, w, K, E, bg_color, Wd1, bd1, Wd2, bd2, Wc1, bc1, Wc2, bc2
  const float* h   = (const float*)d_in[1];
  const float* w   = (const float*)d_in[2];
  const float* K   = (const float*)d_in[3];
  const float* E   = (const float*)d_in[4];
  const float* bg  = (const float*)d_in[5];
  const float* Wd1 = (const float*)d_in[6];
  const float* bd1 = (const float*)d_in[7];
  const float* Wd2 = (const float*)d_in[8];
  const float* bd2 = (const float*)d_in[9];
  const float* Wc1 = (const float*)d_in[10];
  const float* bc1 = (const float*)d_in[11];
  const float* Wc2 = (const float*)d_in[12];
  const float* bc2 = (const float*)d_in[13];
  const int n_rays = in_sizes[1];

  nerf_fwd<<<n_rays, NT, 0, stream>>>(h, w, K, E, bg, Wd1, bd1, Wd2, bd2,
                                      Wc1, bc1, Wc2, bc2,
                                      (float*)d_out, n_rays);
}

// Round 9
// 228.543 us; speedup vs baseline: 17.8866x; 1.0741x over previous
//
#include <hip/hip_runtime.h>
#include <stdint.h>

#define SC 192      // coarse samples (128 + 64)
#define SF 128      // fine (importance) samples
#define NT 128      // threads per block = 2 waves

// LDS weight-table offsets (floats)
#define WD1   0     // 96  (3x32 row-major)
#define BD1   96    // 32
#define WD2   128   // 32
#define BD2   160   // 1 (+3 pad)
#define BC1   164   // 32
#define WC2   196   // 96 (32x3)
#define BC2   292   // 3 (+1 pad)
#define WC1T  296   // 96 = Wc1 rows 32..34 (dir rows)
#define HPK   392   // 32x8 packed per-hidden: [Wd1r0,Wd1r1,Wd1r2,bd1, Wd2,pad,pad,pad]
#define SWTOT (392 + 256)

#define HSTRIDE 40  // ushort stride for H rows (16B-aligned frags, bank-friendly)

using short8 = __attribute__((ext_vector_type(8))) short;
using f32x4  = __attribute__((ext_vector_type(4))) float;

// z_log coarse grid
__device__ __forceinline__ float zlog_c(int t) {
  return (t < 128) ? (-1.0f + (float)t * 0.0078125f)
                   : ((float)(t - 128) * 0.015625f);
}
__device__ __forceinline__ float delta_c(int t) {
  if (t >= SC - 1) return 0.0f;
  return zlog_c(t + 1) - zlog_c(t);
}

__device__ __forceinline__ float fast_rcp(float x) { return __builtin_amdgcn_rcpf(x); }
__device__ __forceinline__ float fast_rsq(float x) { return __builtin_amdgcn_rsqf(x); }
__device__ __forceinline__ float exp10_f(float x) { return __expf(x * 2.30258509299f); }
__device__ __forceinline__ float softplus_f(float x) {
  return fmaxf(x, 0.0f) + __logf(1.0f + __expf(-fabsf(x)));
}

// bf16 RTN-even split helpers (internal precision trick; values finite)
__device__ __forceinline__ unsigned short f2bf(float f) {
  uint32_t u = __float_as_uint(f);
  return (unsigned short)((u + 0x7fffu + ((u >> 16) & 1u)) >> 16);
}
__device__ __forceinline__ float bf2f(unsigned short h) {
  return __uint_as_float(((uint32_t)h) << 16);
}

__device__ __forceinline__ float4 ldsf4(const float* p) { return *(const float4*)p; }

// JAX threefry2x32 with key = (0, 42)
__device__ __forceinline__ void threefry2x32_k42(uint32_t& x0, uint32_t& x1) {
  const uint32_t ks0 = 0u, ks1 = 42u;
  const uint32_t ks2 = ks0 ^ ks1 ^ 0x1BD11BDAu;
  const uint32_t ks[3] = {ks0, ks1, ks2};
  const int rot[2][4] = {{13, 15, 26, 6}, {17, 29, 16, 24}};
  x0 += ks[0];
  x1 += ks[1];
#pragma unroll
  for (int i = 0; i < 5; ++i) {
#pragma unroll
    for (int j = 0; j < 4; ++j) {
      x0 += x1;
      const int r = rot[i & 1][j];
      x1 = (x1 << r) | (x1 >> (32 - r));
      x1 ^= x0;
    }
    x0 += ks[(i + 1) % 3];
    x1 += ks[(i + 2) % 3] + (uint32_t)(i + 1);
  }
}

__device__ __forceinline__ float wave_scan_mul(float v, int lane) {
#pragma unroll
  for (int d = 1; d < 64; d <<= 1) {
    float o = __shfl_up(v, d, 64);
    if (lane >= d) v *= o;
  }
  return v;
}
__device__ __forceinline__ float wave_scan_add(float v, int lane) {
#pragma unroll
  for (int d = 1; d < 64; d <<= 1) {
    float o = __shfl_up(v, d, 64);
    if (lane >= d) v += o;
  }
  return v;
}

// coarse density: float4 LDS reads, unroll 1 to bound live ranges (r7 lesson)
__device__ __forceinline__ float density_sigma_lds(
    float px, float py, float pz, const float* sw, float bd2v) {
  float acc = bd2v;
#pragma unroll 1
  for (int c = 0; c < 8; ++c) {
    const int k4 = c * 4;
    const float4 w0 = ldsf4(sw + WD1 + k4);
    const float4 w1 = ldsf4(sw + WD1 + 32 + k4);
    const float4 w2 = ldsf4(sw + WD1 + 64 + k4);
    const float4 b  = ldsf4(sw + BD1 + k4);
    const float4 wd = ldsf4(sw + WD2 + k4);
    float v;
    v = b.x + px * w0.x + py * w1.x + pz * w2.x; acc += fmaxf(v, 0.0f) * wd.x;
    v = b.y + px * w0.y + py * w1.y + pz * w2.y; acc += fmaxf(v, 0.0f) * wd.y;
    v = b.z + px * w0.z + py * w1.z + pz * w2.z; acc += fmaxf(v, 0.0f) * wd.z;
    v = b.w + px * w0.w + py * w1.w + pz * w2.w; acc += fmaxf(v, 0.0f) * wd.w;
  }
  return softplus_f(acc);
}

__global__ __launch_bounds__(NT) void nerf_fwd(
    const float* __restrict__ hh, const float* __restrict__ ww,
    const float* __restrict__ K, const float* __restrict__ E,
    const float* __restrict__ bg,
    const float* __restrict__ Wd1, const float* __restrict__ bd1,
    const float* __restrict__ Wd2, const float* __restrict__ bd2,
    const float* __restrict__ Wc1, const float* __restrict__ bc1,
    const float* __restrict__ Wc2, const float* __restrict__ bc2,
    float* __restrict__ out, int n_rays) {
  const int ray = blockIdx.x;
  const int t = threadIdx.x;
  const int lane = t & 63;
  const int wv = t >> 6;   // 0 or 1
  const int quad = lane >> 4;

  __shared__ float sw[SWTOT];
  __shared__ __align__(16) unsigned short s_hhi[SF * HSTRIDE];  // fine h, bf16 hi
  __shared__ __align__(16) unsigned short s_hlo[SF * HSTRIDE];  // fine h, bf16 lo residual
  __shared__ uint4 s_bpk[2][2][64];   // Wc1[0:32][:] as MFMA A-frags: [hi/lo][ntile][lane]
  __shared__ float s_rgb4[SF * 4];    // fine rgb (stride 4)
  __shared__ float s_w[SC];
  __shared__ float s_cdf[SC];
  __shared__ float s_zlf[SF];
  __shared__ float s_tot[8];
  __shared__ float s_red[16];

  // ---- stage weights into LDS (once per block) ----
  for (int i = t; i < 96; i += NT)   sw[WD1 + i] = Wd1[i];
  for (int i = t; i < 32; i += NT) { sw[BD1 + i] = bd1[i]; sw[WD2 + i] = Wd2[i]; sw[BC1 + i] = bc1[i]; }
  if (t == 0) sw[BD2] = bd2[0];
  for (int i = t; i < 96; i += NT) { sw[WC2 + i] = Wc2[i]; sw[WC1T + i] = Wc1[32 * 32 + i]; }
  for (int i = t; i < 3; i += NT)    sw[BC2 + i] = bc2[i];
  if (t < 32) {  // packed per-hidden table for fine density
    sw[HPK + t * 8 + 0] = Wd1[t];
    sw[HPK + t * 8 + 1] = Wd1[32 + t];
    sw[HPK + t * 8 + 2] = Wd1[64 + t];
    sw[HPK + t * 8 + 3] = bd1[t];
    sw[HPK + t * 8 + 4] = Wd2[t];
  }
  // pack Wc1[0:32][:] into A-frags (hi/lo): A[m=n][k], lane: n=nt*16+(lane&15), k=quad*8+j
  {
    const int lane_s = t & 63, nt_s = t >> 6;
    const int q_s = lane_s >> 4, n_s = nt_s * 16 + (lane_s & 15);
    uint32_t hwv[4], lwv[4];
#pragma unroll
    for (int j2 = 0; j2 < 4; ++j2) {
      uint32_t hp = 0, lp = 0;
#pragma unroll
      for (int b = 0; b < 2; ++b) {
        const int k = q_s * 8 + j2 * 2 + b;
        const float wval = Wc1[k * 32 + n_s];
        const unsigned short hb = f2bf(wval);
        const unsigned short lb = f2bf(wval - bf2f(hb));
        hp |= ((uint32_t)hb) << (16 * b);
        lp |= ((uint32_t)lb) << (16 * b);
      }
      hwv[j2] = hp; lwv[j2] = lp;
    }
    s_bpk[0][nt_s][lane_s] = make_uint4(hwv[0], hwv[1], hwv[2], hwv[3]);
    s_bpk[1][nt_s][lane_s] = make_uint4(lwv[0], lwv[1], lwv[2], lwv[3]);
  }

  // ---- ray setup (block-uniform) ----
  const float k00 = K[0], k01 = K[1], k02 = K[2];
  const float k10 = K[3], k11 = K[4], k12 = K[5];
  const float k20 = K[6], k21 = K[7], k22 = K[8];
  const float det = k00 * (k11 * k22 - k12 * k21)
                  - k01 * (k10 * k22 - k12 * k20)
                  + k02 * (k10 * k21 - k11 * k20);
  const float id = 1.0f / det;
  const float i00 =  (k11 * k22 - k12 * k21) * id;
  const float i01 = -(k01 * k22 - k02 * k21) * id;
  const float i02 =  (k01 * k12 - k02 * k11) * id;
  const float i10 = -(k10 * k22 - k12 * k20) * id;
  const float i11 =  (k00 * k22 - k02 * k20) * id;
  const float i12 = -(k00 * k12 - k02 * k10) * id;
  const float i20 =  (k10 * k21 - k11 * k20) * id;
  const float i21 = -(k00 * k21 - k01 * k20) * id;
  const float i22 =  (k00 * k11 - k01 * k10) * id;

  const float dwx = ww[ray] + 0.5f;
  const float dwy = hh[ray] + 0.5f;
  const float cx = i00 * dwx + i01 * dwy + i02;
  const float cy = i10 * dwx + i11 * dwy + i12;
  const float cz = i20 * dwx + i21 * dwy + i22;
  const float* Er = E + (size_t)ray * 16;
  const float ox = Er[3], oy = Er[7], oz = Er[11];
  const float dx = Er[0] * cx + Er[1] * cy + Er[2] * cz;
  const float dy = Er[4] * cx + Er[5] * cy + Er[6] * cz;
  const float dz = Er[8] * cx + Er[9] * cy + Er[10] * cz;
  const float inv_nrm = fast_rsq(dx * dx + dy * dy + dz * dz);
  const float ndx = dx * inv_nrm, ndy = dy * inv_nrm, ndz = dz * inv_nrm;

  __syncthreads();   // weights + frags staged

  // ---- coarse pass ----
  const float bd2v = sw[BD2];
  float a0, v0, a1e = 0.0f, v1e = 1.0f;
  {
    const float z = exp10_f(zlog_c(t));
    float px = ox + dx * z, py = oy + dy * z, pz = oz + dz * z;
    const float dist = sqrtf(px * px + py * py + pz * pz);
    if (dist > 1.0f) {
      const float invd = fast_rcp(dist);
      const float sc = (2.0f - invd) * invd;
      px *= sc; py *= sc; pz *= sc;
    }
    const float sig = density_sigma_lds(px, py, pz, sw, bd2v);
    v0 = __expf(-sig * delta_c(t));
    a0 = 1.0f - v0;
  }
  if (wv == 0) {
    const int e = 128 + t;
    const float z = exp10_f(zlog_c(e));
    float px = ox + dx * z, py = oy + dy * z, pz = oz + dz * z;
    const float dist = sqrtf(px * px + py * py + pz * pz);
    if (dist > 1.0f) {
      const float invd = fast_rcp(dist);
      const float sc = (2.0f - invd) * invd;
      px *= sc; py *= sc; pz *= sc;
    }
    const float sig = density_sigma_lds(px, py, pz, sw, bd2v);
    v1e = __expf(-sig * delta_c(e));
    a1e = 1.0f - v1e;
  }

  // parallel cumprod of (1-alpha)
  float i0 = wave_scan_mul(v0, lane);
  float i1 = 1.0f;
  if (wv == 0) i1 = wave_scan_mul(v1e, lane);
  if (lane == 63) s_tot[wv] = i0;
  if (wv == 0 && lane == 63) s_tot[2] = i1;
  __syncthreads();
  {
    const float preC1 = s_tot[0];
    const float preC2 = s_tot[0] * s_tot[1];
    float e0x = __shfl_up(i0, 1, 64); if (lane == 0) e0x = 1.0f;
    s_w[t] = a0 * e0x * (wv ? preC1 : 1.0f);
    if (wv == 0) {
      float e1x = __shfl_up(i1, 1, 64); if (lane == 0) e1x = 1.0f;
      s_w[128 + t] = a1e * e1x * preC2;
    }
  }
  __syncthreads();

  // reweight
  float wre0, wre1 = 0.0f;
  {
    const float wm = (t > 0) ? s_w[t - 1] : 0.0f;
    const float w0 = s_w[t];
    const float wp = s_w[t + 1];
    wre0 = 0.5f * (fmaxf(wm, w0) + fmaxf(w0, wp)) + (0.02f / 192.0f);
    wre0 *= (t < 128) ? (128.0f / 192.0f) : (64.0f / 192.0f);
  }
  if (wv == 0) {
    const int e = 128 + t;
    const float wm = s_w[e - 1];
    const float w0 = s_w[e];
    const float wp = (e < SC - 1) ? s_w[e + 1] : 0.0f;
    wre1 = 0.5f * (fmaxf(wm, w0) + fmaxf(w0, wp)) + (0.02f / 192.0f);
    wre1 *= (64.0f / 192.0f);
  }

  // parallel cumsum -> normalized CDF
  float s0 = wave_scan_add(wre0, lane);
  float s1 = 0.0f;
  if (wv == 0) s1 = wave_scan_add(wre1, lane);
  if (lane == 63) s_tot[4 + wv] = s0;
  if (wv == 0 && lane == 63) s_tot[6] = s1;
  __syncthreads();
  {
    const float T0 = s_tot[4], T1 = s_tot[5], T2 = s_tot[6];
    const float inv_total = fast_rcp(T0 + T1 + T2);
    s_cdf[t] = (s0 + (wv ? T0 : 0.0f)) * inv_total;
    if (wv == 0) s_cdf[128 + t] = (s1 + T0 + T1) * inv_total;
  }
  __syncthreads();

  // ---- importance sampling ----
  float zlf, zf;
  {
    const uint32_t total = (uint32_t)n_rays * 128u;
    const uint32_t halfc = total >> 1;
    const uint32_t j = (uint32_t)ray * 128u + (uint32_t)t;
    uint32_t x0, x1;
    const bool first = (j < halfc);
    if (first) { x0 = j; x1 = j + halfc; } else { x0 = j - halfc; x1 = j; }
    threefry2x32_k42(x0, x1);
    const uint32_t bits = first ? x0 : x1;
    const float fr = __uint_as_float((bits >> 9) | 0x3f800000u) - 1.0f;

    float u = (float)t * 0.0078125f + fr * 0.0078125f;
    u = u * (s_cdf[190] - s_cdf[1]) + s_cdf[1];

    int lo = 0, hi = 189;
    while (lo < hi) {
      const int mid = (lo + hi) >> 1;
      if (s_cdf[1 + mid] <= u) lo = mid + 1; else hi = mid;
    }
    const int inds = lo + 1;
    const float cb = s_cdf[inds - 1], ca = s_cdf[inds];
    const float tt = (u - cb) * fast_rcp(ca - cb);
    const float zb = 0.5f * (zlog_c(inds - 1) + zlog_c(inds));
    const float za = 0.5f * (zlog_c(inds) + zlog_c(inds + 1));
    zlf = zb + (za - zb) * tt;
    s_zlf[t] = zlf;
    zf = exp10_f(zlf);
  }
  __syncthreads();

  // ---- fine density per-thread; h -> LDS as bf16 hi/lo (B-frag layout) ----
  float sigf;
  {
    float px = ox + dx * zf, py = oy + dy * zf, pz = oz + dz * zf;
    const float dist = sqrtf(px * px + py * py + pz * pz);
    if (dist > 1.0f) {
      const float invd = fast_rcp(dist);
      const float sc = (2.0f - invd) * invd;
      px *= sc; py *= sc; pz *= sc;
    }
    float sig_acc = bd2v;
#pragma unroll
    for (int c = 0; c < 4; ++c) {
      uint32_t hwv[4], lwv[4];
#pragma unroll
      for (int j2 = 0; j2 < 4; ++j2) {
        uint32_t hp = 0, lp = 0;
#pragma unroll
        for (int b = 0; b < 2; ++b) {
          const int i = c * 8 + j2 * 2 + b;
          const float4 hpk = ldsf4(sw + HPK + i * 8);
          const float wd2i = sw[HPK + i * 8 + 4];
          float hv = hpk.w + px * hpk.x + py * hpk.y + pz * hpk.z;
          hv = fmaxf(hv, 0.0f);
          sig_acc += hv * wd2i;
          const unsigned short hb = f2bf(hv);
          const unsigned short lb = f2bf(hv - bf2f(hb));
          hp |= ((uint32_t)hb) << (16 * b);
          lp |= ((uint32_t)lb) << (16 * b);
        }
        hwv[j2] = hp; lwv[j2] = lp;
      }
      *(uint4*)(s_hhi + t * HSTRIDE + c * 8) = make_uint4(hwv[0], hwv[1], hwv[2], hwv[3]);
      *(uint4*)(s_hlo + t * HSTRIDE + c * 8) = make_uint4(lwv[0], lwv[1], lwv[2], lwv[3]);
    }
    sigf = softplus_f(sig_acc);
  }
  __syncthreads();   // h staged for MFMA

  // ---- fine color via MFMA: a1^T[32 x 128] = Wc1^T . H^T (bf16 hi/lo split) ----
  {
    const short8 Whi0 = *(const short8*)&s_bpk[0][0][lane];
    const short8 Whi1 = *(const short8*)&s_bpk[0][1][lane];
    const short8 Wlo0 = *(const short8*)&s_bpk[1][0][lane];
    const short8 Wlo1 = *(const short8*)&s_bpk[1][1][lane];

    // per-lane n-values: n = nt*16 + quad*4 + r  (C rows this lane will own)
    float dvv[2][4], w2v[2][4][3];
#pragma unroll
    for (int nt = 0; nt < 2; ++nt)
#pragma unroll
      for (int r = 0; r < 4; ++r) {
        const int n = nt * 16 + quad * 4 + r;
        dvv[nt][r] = sw[BC1 + n] + ndx * sw[WC1T + n]
                   + ndy * sw[WC1T + 32 + n] + ndz * sw[WC1T + 64 + n];
#pragma unroll
        for (int c = 0; c < 3; ++c) w2v[nt][r][c] = sw[WC2 + n * 3 + c];
      }

#pragma unroll
    for (int mt = 0; mt < 4; ++mt) {
      const int sbase = wv * 64 + mt * 16;
      const int srow = sbase + (lane & 15);
      const short8 Hhi = *(const short8*)(s_hhi + srow * HSTRIDE + quad * 8);
      const short8 Hlo = *(const short8*)(s_hlo + srow * HSTRIDE + quad * 8);

      f32x4 acc0 = {0.f, 0.f, 0.f, 0.f}, acc1 = {0.f, 0.f, 0.f, 0.f};
      acc0 = __builtin_amdgcn_mfma_f32_16x16x32_bf16(Whi0, Hhi, acc0, 0, 0, 0);
      acc0 = __builtin_amdgcn_mfma_f32_16x16x32_bf16(Whi0, Hlo, acc0, 0, 0, 0);
      acc0 = __builtin_amdgcn_mfma_f32_16x16x32_bf16(Wlo0, Hhi, acc0, 0, 0, 0);
      acc1 = __builtin_amdgcn_mfma_f32_16x16x32_bf16(Whi1, Hhi, acc1, 0, 0, 0);
      acc1 = __builtin_amdgcn_mfma_f32_16x16x32_bf16(Whi1, Hlo, acc1, 0, 0, 0);
      acc1 = __builtin_amdgcn_mfma_f32_16x16x32_bf16(Wlo1, Hhi, acc1, 0, 0, 0);

      // layer2 partial over this lane's 8 n-values (in-register)
      float pc0 = 0.f, pc1 = 0.f, pc2 = 0.f;
#pragma unroll
      for (int r = 0; r < 4; ++r) {
        const float av0 = fmaxf(acc0[r] + dvv[0][r], 0.0f);
        const float av1 = fmaxf(acc1[r] + dvv[1][r], 0.0f);
        pc0 += av0 * w2v[0][r][0] + av1 * w2v[1][r][0];
        pc1 += av0 * w2v[0][r][1] + av1 * w2v[1][r][1];
        pc2 += av0 * w2v[0][r][2] + av1 * w2v[1][r][2];
      }
      // reduce over the 4 quads (same sample lives at lane&15 across quads)
#pragma unroll
      for (int mask = 16; mask < 64; mask <<= 1) {
        pc0 += __shfl_xor(pc0, mask, 64);
        pc1 += __shfl_xor(pc1, mask, 64);
        pc2 += __shfl_xor(pc2, mask, 64);
      }
      // write rgb: lane < 48 writes (s = lane&15, c = lane>>4)
      const int cidx = lane >> 4;
      const float oc = (cidx == 0) ? pc0 : ((cidx == 1) ? pc1 : pc2);
      if (lane < 48) {
        const int s = sbase + (lane & 15);
        const float o = oc + sw[BC2 + cidx];
        s_rgb4[s * 4 + cidx] = fast_rcp(1.0f + __expf(-o));
      }
    }
  }

  // ---- fine alpha + parallel cumprod over 128 ----
  const float deltaf = (t < SF - 1) ? (s_zlf[t + 1] - zlf) : 0.0f;
  const float vf = __expf(-sigf * deltaf);
  const float af = 1.0f - vf;
  float fi = wave_scan_mul(vf, lane);
  if (lane == 63) s_tot[wv] = fi;
  __syncthreads();   // also makes s_rgb4 visible
  float efx = __shfl_up(fi, 1, 64); if (lane == 0) efx = 1.0f;
  const float wf = af * efx * (wv ? s_tot[0] : 1.0f);

  // ---- outputs ----
  float* o_img = out;
  float* o_w   = out + (size_t)n_rays * 3;
  float* o_z   = out + (size_t)n_rays * (3 + 128);
  float* o_inv = out + (size_t)n_rays * (3 + 256);

  o_w[(size_t)ray * 128 + t] = wf;
  o_z[(size_t)ray * 128 + t] = (zlf + 1.0f) * 0.5f;

  float r0 = wf * s_rgb4[t * 4 + 0];
  float r1 = wf * s_rgb4[t * 4 + 1];
  float r2 = wf * s_rgb4[t * 4 + 2];
  float r3 = wf, r4 = wf * fast_rcp(zf);
#pragma unroll
  for (int d = 32; d > 0; d >>= 1) {
    r0 += __shfl_down(r0, d, 64);
    r1 += __shfl_down(r1, d, 64);
    r2 += __shfl_down(r2, d, 64);
    r3 += __shfl_down(r3, d, 64);
    r4 += __shfl_down(r4, d, 64);
  }
  if (lane == 0) {
    float* p = &s_red[wv * 5];
    p[0] = r0; p[1] = r1; p[2] = r2; p[3] = r3; p[4] = r4;
  }
  __syncthreads();
  if (t == 0) {
    const float accw = s_red[3] + s_red[8];
    const float bgw = 1.0f - accw;
    o_img[(size_t)ray * 3 + 0] = (s_red[0] + s_red[5]) + bgw * bg[0];
    o_img[(size_t)ray * 3 + 1] = (s_red[1] + s_red[6]) + bgw * bg[1];
    o_img[(size_t)ray * 3 + 2] = (s_red[2] + s_red[7]) + bgw * bg[2];
    o_inv[ray] = s_red[4] + s_red[9];
  }
}

extern "C" void kernel_launch(void* const* d_in, const int* in_sizes, int n_in,
                              void* d_out, int out_size, void* d_ws, size_t ws_size,
                              hipStream_t stream) {
  const float* h   = (const float*)d_in[1];
  const float* w   = (const float*)d_in[2];
  const float* K   = (const float*)d_in[3];
  const float* E   = (const float*)d_in[4];
  const float* bg  = (const float*)d_in[5];
  const float* Wd1 = (const float*)d_in[6];
  const float* bd1 = (const float*)d_in[7];
  const float* Wd2 = (const float*)d_in[8];
  const float* bd2 = (const float*)d_in[9];
  const float* Wc1 = (const float*)d_in[10];
  const float* bc1 = (const float*)d_in[11];
  const float* Wc2 = (const float*)d_in[12];
  const float* bc2 = (const float*)d_in[13];
  const int n_rays = in_sizes[1];

  nerf_fwd<<<n_rays, NT, 0, stream>>>(h, w, K, E, bg, Wd1, bd1, Wd2, bd2,
                                      Wc1, bc1, Wc2, bc2,
                                      (float*)d_out, n_rays);
}

// Round 10
// 193.116 us; speedup vs baseline: 21.1680x; 1.1835x over previous
//
#include <hip/hip_runtime.h>
#include <stdint.h>

#define SC 192      // coarse samples (128 + 64)
#define SF 128      // fine (importance) samples
#define NT 128      // threads per block = 2 waves

// LDS weight-table offsets (floats)
#define WD1   0     // 96  (3x32 row-major)
#define BD1   96    // 32
#define WD2   128   // 32
#define BD2   160   // 1 (+3 pad)
#define BC1   164   // 32
#define WC2   196   // 96 (32x3)
#define BC2   292   // 3 (+1 pad)
#define WC1T  296   // 96 = Wc1 rows 32..34 (dir rows)
#define HPK   392   // 32x8 packed per-hidden: [Wd1r0,Wd1r1,Wd1r2,bd1, Wd2,pad,pad,pad]
#define SWTOT (392 + 256)

#define HSTRIDE 40  // ushort stride for H rows (16B-aligned frags)
#define RGBS 5      // s_rgb stride (floats) — 4 caused 8-way bank conflicts

using short8 = __attribute__((ext_vector_type(8))) short;
using f32x4  = __attribute__((ext_vector_type(4))) float;

// z_log coarse grid
__device__ __forceinline__ float zlog_c(int t) {
  return (t < 128) ? (-1.0f + (float)t * 0.0078125f)
                   : ((float)(t - 128) * 0.015625f);
}
__device__ __forceinline__ float delta_c(int t) {
  if (t >= SC - 1) return 0.0f;
  return zlog_c(t + 1) - zlog_c(t);
}

__device__ __forceinline__ float fast_rcp(float x) { return __builtin_amdgcn_rcpf(x); }
__device__ __forceinline__ float fast_rsq(float x) { return __builtin_amdgcn_rsqf(x); }
__device__ __forceinline__ float exp10_f(float x) { return __expf(x * 2.30258509299f); }
__device__ __forceinline__ float softplus_f(float x) {
  return fmaxf(x, 0.0f) + __logf(1.0f + __expf(-fabsf(x)));
}

// bf16 RTN-even split helpers
__device__ __forceinline__ unsigned short f2bf(float f) {
  uint32_t u = __float_as_uint(f);
  return (unsigned short)((u + 0x7fffu + ((u >> 16) & 1u)) >> 16);
}
__device__ __forceinline__ float bf2f(unsigned short h) {
  return __uint_as_float(((uint32_t)h) << 16);
}

__device__ __forceinline__ float4 ldsf4(const float* p) { return *(const float4*)p; }

// JAX threefry2x32 with key = (0, 42)
__device__ __forceinline__ void threefry2x32_k42(uint32_t& x0, uint32_t& x1) {
  const uint32_t ks0 = 0u, ks1 = 42u;
  const uint32_t ks2 = ks0 ^ ks1 ^ 0x1BD11BDAu;
  const uint32_t ks[3] = {ks0, ks1, ks2};
  const int rot[2][4] = {{13, 15, 26, 6}, {17, 29, 16, 24}};
  x0 += ks[0];
  x1 += ks[1];
#pragma unroll
  for (int i = 0; i < 5; ++i) {
#pragma unroll
    for (int j = 0; j < 4; ++j) {
      x0 += x1;
      const int r = rot[i & 1][j];
      x1 = (x1 << r) | (x1 >> (32 - r));
      x1 ^= x0;
    }
    x0 += ks[(i + 1) % 3];
    x1 += ks[(i + 2) % 3] + (uint32_t)(i + 1);
  }
}

__device__ __forceinline__ float wave_scan_mul(float v, int lane) {
#pragma unroll
  for (int d = 1; d < 64; d <<= 1) {
    float o = __shfl_up(v, d, 64);
    if (lane >= d) v *= o;
  }
  return v;
}
__device__ __forceinline__ float wave_scan_add(float v, int lane) {
#pragma unroll
  for (int d = 1; d < 64; d <<= 1) {
    float o = __shfl_up(v, d, 64);
    if (lane >= d) v += o;
  }
  return v;
}

// coarse density: float4 LDS reads; unroll 2 for ds_read ILP (VGPR headroom ok)
__device__ __forceinline__ float density_sigma_lds(
    float px, float py, float pz, const float* sw, float bd2v) {
  float acc = bd2v;
#pragma unroll 2
  for (int c = 0; c < 8; ++c) {
    const int k4 = c * 4;
    const float4 w0 = ldsf4(sw + WD1 + k4);
    const float4 w1 = ldsf4(sw + WD1 + 32 + k4);
    const float4 w2 = ldsf4(sw + WD1 + 64 + k4);
    const float4 b  = ldsf4(sw + BD1 + k4);
    const float4 wd = ldsf4(sw + WD2 + k4);
    float v;
    v = b.x + px * w0.x + py * w1.x + pz * w2.x; acc += fmaxf(v, 0.0f) * wd.x;
    v = b.y + px * w0.y + py * w1.y + pz * w2.y; acc += fmaxf(v, 0.0f) * wd.y;
    v = b.z + px * w0.z + py * w1.z + pz * w2.z; acc += fmaxf(v, 0.0f) * wd.z;
    v = b.w + px * w0.w + py * w1.w + pz * w2.w; acc += fmaxf(v, 0.0f) * wd.w;
  }
  return softplus_f(acc);
}

__global__ __launch_bounds__(NT) void nerf_fwd(
    const float* __restrict__ hh, const float* __restrict__ ww,
    const float* __restrict__ K, const float* __restrict__ E,
    const float* __restrict__ bg,
    const float* __restrict__ Wd1, const float* __restrict__ bd1,
    const float* __restrict__ Wd2, const float* __restrict__ bd2,
    const float* __restrict__ Wc1, const float* __restrict__ bc1,
    const float* __restrict__ Wc2, const float* __restrict__ bc2,
    float* __restrict__ out, int n_rays) {
  const int ray = blockIdx.x;
  const int t = threadIdx.x;
  const int lane = t & 63;
  const int wv = t >> 6;   // 0 or 1
  const int quad = lane >> 4;

  __shared__ float sw[SWTOT];
  __shared__ __align__(16) unsigned short s_hhi[SF * HSTRIDE];  // fine h, bf16 (hi only)
  __shared__ uint4 s_bpk[2][2][64];   // Wc1[0:32][:] as MFMA A-frags: [hi/lo][ntile][lane]
  __shared__ float s_rgb[SF * RGBS];  // fine rgb (stride 5, conflict-free)
  __shared__ float s_w[SC];
  __shared__ float s_cdf[SC];
  __shared__ float s_zlf[SF];
  __shared__ float s_tot[8];
  __shared__ float s_red[16];

  // ---- stage weights into LDS (once per block) ----
  for (int i = t; i < 96; i += NT)   sw[WD1 + i] = Wd1[i];
  for (int i = t; i < 32; i += NT) { sw[BD1 + i] = bd1[i]; sw[WD2 + i] = Wd2[i]; sw[BC1 + i] = bc1[i]; }
  if (t == 0) sw[BD2] = bd2[0];
  for (int i = t; i < 96; i += NT) { sw[WC2 + i] = Wc2[i]; sw[WC1T + i] = Wc1[32 * 32 + i]; }
  for (int i = t; i < 3; i += NT)    sw[BC2 + i] = bc2[i];
  if (t < 32) {  // packed per-hidden table for fine density
    sw[HPK + t * 8 + 0] = Wd1[t];
    sw[HPK + t * 8 + 1] = Wd1[32 + t];
    sw[HPK + t * 8 + 2] = Wd1[64 + t];
    sw[HPK + t * 8 + 3] = bd1[t];
    sw[HPK + t * 8 + 4] = Wd2[t];
  }
  // pack Wc1[0:32][:] into A-frags (hi/lo): A[m=n][k], lane: n=nt*16+(lane&15), k=quad*8+j
  {
    const int lane_s = t & 63, nt_s = t >> 6;
    const int q_s = lane_s >> 4, n_s = nt_s * 16 + (lane_s & 15);
    uint32_t hwv[4], lwv[4];
#pragma unroll
    for (int j2 = 0; j2 < 4; ++j2) {
      uint32_t hp = 0, lp = 0;
#pragma unroll
      for (int b = 0; b < 2; ++b) {
        const int k = q_s * 8 + j2 * 2 + b;
        const float wval = Wc1[k * 32 + n_s];
        const unsigned short hb = f2bf(wval);
        const unsigned short lb = f2bf(wval - bf2f(hb));
        hp |= ((uint32_t)hb) << (16 * b);
        lp |= ((uint32_t)lb) << (16 * b);
      }
      hwv[j2] = hp; lwv[j2] = lp;
    }
    s_bpk[0][nt_s][lane_s] = make_uint4(hwv[0], hwv[1], hwv[2], hwv[3]);
    s_bpk[1][nt_s][lane_s] = make_uint4(lwv[0], lwv[1], lwv[2], lwv[3]);
  }

  // ---- ray setup (block-uniform) ----
  const float k00 = K[0], k01 = K[1], k02 = K[2];
  const float k10 = K[3], k11 = K[4], k12 = K[5];
  const float k20 = K[6], k21 = K[7], k22 = K[8];
  const float det = k00 * (k11 * k22 - k12 * k21)
                  - k01 * (k10 * k22 - k12 * k20)
                  + k02 * (k10 * k21 - k11 * k20);
  const float id = 1.0f / det;
  const float i00 =  (k11 * k22 - k12 * k21) * id;
  const float i01 = -(k01 * k22 - k02 * k21) * id;
  const float i02 =  (k01 * k12 - k02 * k11) * id;
  const float i10 = -(k10 * k22 - k12 * k20) * id;
  const float i11 =  (k00 * k22 - k02 * k20) * id;
  const float i12 = -(k00 * k12 - k02 * k10) * id;
  const float i20 =  (k10 * k21 - k11 * k20) * id;
  const float i21 = -(k00 * k21 - k01 * k20) * id;
  const float i22 =  (k00 * k11 - k01 * k10) * id;

  const float dwx = ww[ray] + 0.5f;
  const float dwy = hh[ray] + 0.5f;
  const float cx = i00 * dwx + i01 * dwy + i02;
  const float cy = i10 * dwx + i11 * dwy + i12;
  const float cz = i20 * dwx + i21 * dwy + i22;
  const float* Er = E + (size_t)ray * 16;
  const float ox = Er[3], oy = Er[7], oz = Er[11];
  const float dx = Er[0] * cx + Er[1] * cy + Er[2] * cz;
  const float dy = Er[4] * cx + Er[5] * cy + Er[6] * cz;
  const float dz = Er[8] * cx + Er[9] * cy + Er[10] * cz;
  const float inv_nrm = fast_rsq(dx * dx + dy * dy + dz * dz);
  const float ndx = dx * inv_nrm, ndy = dy * inv_nrm, ndz = dz * inv_nrm;

  __syncthreads();   // weights + frags staged

  // ---- coarse pass ----
  const float bd2v = sw[BD2];
  float a0, v0, a1e = 0.0f, v1e = 1.0f;
  {
    const float z = exp10_f(zlog_c(t));
    float px = ox + dx * z, py = oy + dy * z, pz = oz + dz * z;
    const float dist = sqrtf(px * px + py * py + pz * pz);
    if (dist > 1.0f) {
      const float invd = fast_rcp(dist);
      const float sc = (2.0f - invd) * invd;
      px *= sc; py *= sc; pz *= sc;
    }
    const float sig = density_sigma_lds(px, py, pz, sw, bd2v);
    v0 = __expf(-sig * delta_c(t));
    a0 = 1.0f - v0;
  }
  if (wv == 0) {
    const int e = 128 + t;
    const float z = exp10_f(zlog_c(e));
    float px = ox + dx * z, py = oy + dy * z, pz = oz + dz * z;
    const float dist = sqrtf(px * px + py * py + pz * pz);
    if (dist > 1.0f) {
      const float invd = fast_rcp(dist);
      const float sc = (2.0f - invd) * invd;
      px *= sc; py *= sc; pz *= sc;
    }
    const float sig = density_sigma_lds(px, py, pz, sw, bd2v);
    v1e = __expf(-sig * delta_c(e));
    a1e = 1.0f - v1e;
  }

  // parallel cumprod of (1-alpha)
  float i0 = wave_scan_mul(v0, lane);
  float i1 = 1.0f;
  if (wv == 0) i1 = wave_scan_mul(v1e, lane);
  if (lane == 63) s_tot[wv] = i0;
  if (wv == 0 && lane == 63) s_tot[2] = i1;
  __syncthreads();
  {
    const float preC1 = s_tot[0];
    const float preC2 = s_tot[0] * s_tot[1];
    float e0x = __shfl_up(i0, 1, 64); if (lane == 0) e0x = 1.0f;
    s_w[t] = a0 * e0x * (wv ? preC1 : 1.0f);
    if (wv == 0) {
      float e1x = __shfl_up(i1, 1, 64); if (lane == 0) e1x = 1.0f;
      s_w[128 + t] = a1e * e1x * preC2;
    }
  }
  __syncthreads();

  // reweight
  float wre0, wre1 = 0.0f;
  {
    const float wm = (t > 0) ? s_w[t - 1] : 0.0f;
    const float w0 = s_w[t];
    const float wp = s_w[t + 1];
    wre0 = 0.5f * (fmaxf(wm, w0) + fmaxf(w0, wp)) + (0.02f / 192.0f);
    wre0 *= (t < 128) ? (128.0f / 192.0f) : (64.0f / 192.0f);
  }
  if (wv == 0) {
    const int e = 128 + t;
    const float wm = s_w[e - 1];
    const float w0 = s_w[e];
    const float wp = (e < SC - 1) ? s_w[e + 1] : 0.0f;
    wre1 = 0.5f * (fmaxf(wm, w0) + fmaxf(w0, wp)) + (0.02f / 192.0f);
    wre1 *= (64.0f / 192.0f);
  }

  // parallel cumsum -> normalized CDF
  float s0 = wave_scan_add(wre0, lane);
  float s1 = 0.0f;
  if (wv == 0) s1 = wave_scan_add(wre1, lane);
  if (lane == 63) s_tot[4 + wv] = s0;
  if (wv == 0 && lane == 63) s_tot[6] = s1;
  __syncthreads();
  {
    const float T0 = s_tot[4], T1 = s_tot[5], T2 = s_tot[6];
    const float inv_total = fast_rcp(T0 + T1 + T2);
    s_cdf[t] = (s0 + (wv ? T0 : 0.0f)) * inv_total;
    if (wv == 0) s_cdf[128 + t] = (s1 + T0 + T1) * inv_total;
  }
  __syncthreads();

  // ---- importance sampling ----
  float zlf, zf;
  {
    const uint32_t total = (uint32_t)n_rays * 128u;
    const uint32_t halfc = total >> 1;
    const uint32_t j = (uint32_t)ray * 128u + (uint32_t)t;
    uint32_t x0, x1;
    const bool first = (j < halfc);
    if (first) { x0 = j; x1 = j + halfc; } else { x0 = j - halfc; x1 = j; }
    threefry2x32_k42(x0, x1);
    const uint32_t bits = first ? x0 : x1;
    const float fr = __uint_as_float((bits >> 9) | 0x3f800000u) - 1.0f;

    float u = (float)t * 0.0078125f + fr * 0.0078125f;
    u = u * (s_cdf[190] - s_cdf[1]) + s_cdf[1];

    int lo = 0, hi = 189;
    while (lo < hi) {
      const int mid = (lo + hi) >> 1;
      if (s_cdf[1 + mid] <= u) lo = mid + 1; else hi = mid;
    }
    const int inds = lo + 1;
    const float cb = s_cdf[inds - 1], ca = s_cdf[inds];
    const float tt = (u - cb) * fast_rcp(ca - cb);
    const float zb = 0.5f * (zlog_c(inds - 1) + zlog_c(inds));
    const float za = 0.5f * (zlog_c(inds) + zlog_c(inds + 1));
    zlf = zb + (za - zb) * tt;
    s_zlf[t] = zlf;
    zf = exp10_f(zlf);
  }
  __syncthreads();

  // ---- fine density per-thread; h -> LDS as bf16 (hi only; RTN mean-zero err) ----
  float sigf;
  {
    float px = ox + dx * zf, py = oy + dy * zf, pz = oz + dz * zf;
    const float dist = sqrtf(px * px + py * py + pz * pz);
    if (dist > 1.0f) {
      const float invd = fast_rcp(dist);
      const float sc = (2.0f - invd) * invd;
      px *= sc; py *= sc; pz *= sc;
    }
    float sig_acc = bd2v;
#pragma unroll
    for (int c = 0; c < 4; ++c) {
      uint32_t hwv[4];
#pragma unroll
      for (int j2 = 0; j2 < 4; ++j2) {
        uint32_t hp = 0;
#pragma unroll
        for (int b = 0; b < 2; ++b) {
          const int i = c * 8 + j2 * 2 + b;
          const float4 hpk = ldsf4(sw + HPK + i * 8);
          const float wd2i = sw[HPK + i * 8 + 4];
          float hv = hpk.w + px * hpk.x + py * hpk.y + pz * hpk.z;
          hv = fmaxf(hv, 0.0f);
          sig_acc += hv * wd2i;
          hp |= ((uint32_t)f2bf(hv)) << (16 * b);
        }
        hwv[j2] = hp;
      }
      *(uint4*)(s_hhi + t * HSTRIDE + c * 8) = make_uint4(hwv[0], hwv[1], hwv[2], hwv[3]);
    }
    sigf = softplus_f(sig_acc);
  }
  __syncthreads();   // h staged for MFMA

  // ---- fine color via MFMA: a1^T[32 x 128] = Wc1^T . H^T (W hi+lo, H hi) ----
  {
    const short8 Whi0 = *(const short8*)&s_bpk[0][0][lane];
    const short8 Whi1 = *(const short8*)&s_bpk[0][1][lane];
    const short8 Wlo0 = *(const short8*)&s_bpk[1][0][lane];
    const short8 Wlo1 = *(const short8*)&s_bpk[1][1][lane];

    // per-lane n-values: n = nt*16 + quad*4 + r
    float dvv[2][4], w2v[2][4][3];
#pragma unroll
    for (int nt = 0; nt < 2; ++nt)
#pragma unroll
      for (int r = 0; r < 4; ++r) {
        const int n = nt * 16 + quad * 4 + r;
        dvv[nt][r] = sw[BC1 + n] + ndx * sw[WC1T + n]
                   + ndy * sw[WC1T + 32 + n] + ndz * sw[WC1T + 64 + n];
#pragma unroll
        for (int c = 0; c < 3; ++c) w2v[nt][r][c] = sw[WC2 + n * 3 + c];
      }

#pragma unroll
    for (int mt = 0; mt < 4; ++mt) {
      const int sbase = wv * 64 + mt * 16;
      const int srow = sbase + (lane & 15);
      const short8 Hhi = *(const short8*)(s_hhi + srow * HSTRIDE + quad * 8);

      f32x4 acc0 = {0.f, 0.f, 0.f, 0.f}, acc1 = {0.f, 0.f, 0.f, 0.f};
      acc0 = __builtin_amdgcn_mfma_f32_16x16x32_bf16(Whi0, Hhi, acc0, 0, 0, 0);
      acc0 = __builtin_amdgcn_mfma_f32_16x16x32_bf16(Wlo0, Hhi, acc0, 0, 0, 0);
      acc1 = __builtin_amdgcn_mfma_f32_16x16x32_bf16(Whi1, Hhi, acc1, 0, 0, 0);
      acc1 = __builtin_amdgcn_mfma_f32_16x16x32_bf16(Wlo1, Hhi, acc1, 0, 0, 0);

      // layer2 partial over this lane's 8 n-values (in-register)
      float pc0 = 0.f, pc1 = 0.f, pc2 = 0.f;
#pragma unroll
      for (int r = 0; r < 4; ++r) {
        const float av0 = fmaxf(acc0[r] + dvv[0][r], 0.0f);
        const float av1 = fmaxf(acc1[r] + dvv[1][r], 0.0f);
        pc0 += av0 * w2v[0][r][0] + av1 * w2v[1][r][0];
        pc1 += av0 * w2v[0][r][1] + av1 * w2v[1][r][1];
        pc2 += av0 * w2v[0][r][2] + av1 * w2v[1][r][2];
      }
      // reduce over the 4 quads
#pragma unroll
      for (int mask = 16; mask < 64; mask <<= 1) {
        pc0 += __shfl_xor(pc0, mask, 64);
        pc1 += __shfl_xor(pc1, mask, 64);
        pc2 += __shfl_xor(pc2, mask, 64);
      }
      const int cidx = lane >> 4;
      const float oc = (cidx == 0) ? pc0 : ((cidx == 1) ? pc1 : pc2);
      if (lane < 48) {
        const int s = sbase + (lane & 15);
        const float o = oc + sw[BC2 + cidx];
        s_rgb[s * RGBS + cidx] = fast_rcp(1.0f + __expf(-o));
      }
    }
  }

  // ---- fine alpha + parallel cumprod over 128 ----
  const float deltaf = (t < SF - 1) ? (s_zlf[t + 1] - zlf) : 0.0f;
  const float vf = __expf(-sigf * deltaf);
  const float af = 1.0f - vf;
  float fi = wave_scan_mul(vf, lane);
  if (lane == 63) s_tot[wv] = fi;
  __syncthreads();   // also makes s_rgb visible
  float efx = __shfl_up(fi, 1, 64); if (lane == 0) efx = 1.0f;
  const float wf = af * efx * (wv ? s_tot[0] : 1.0f);

  // ---- outputs ----
  float* o_img = out;
  float* o_w   = out + (size_t)n_rays * 3;
  float* o_z   = out + (size_t)n_rays * (3 + 128);
  float* o_inv = out + (size_t)n_rays * (3 + 256);

  o_w[(size_t)ray * 128 + t] = wf;
  o_z[(size_t)ray * 128 + t] = (zlf + 1.0f) * 0.5f;

  float r0 = wf * s_rgb[t * RGBS + 0];
  float r1 = wf * s_rgb[t * RGBS + 1];
  float r2 = wf * s_rgb[t * RGBS + 2];
  float r3 = wf, r4 = wf * fast_rcp(zf);
#pragma unroll
  for (int d = 32; d > 0; d >>= 1) {
    r0 += __shfl_down(r0, d, 64);
    r1 += __shfl_down(r1, d, 64);
    r2 += __shfl_down(r2, d, 64);
    r3 += __shfl_down(r3, d, 64);
    r4 += __shfl_down(r4, d, 64);
  }
  if (lane == 0) {
    float* p = &s_red[wv * 5];
    p[0] = r0; p[1] = r1; p[2] = r2; p[3] = r3; p[4] = r4;
  }
  __syncthreads();
  if (t == 0) {
    const float accw = s_red[3] + s_red[8];
    const float bgw = 1.0f - accw;
    o_img[(size_t)ray * 3 + 0] = (s_red[0] + s_red[5]) + bgw * bg[0];
    o_img[(size_t)ray * 3 + 1] = (s_red[1] + s_red[6]) + bgw * bg[1];
    o_img[(size_t)ray * 3 + 2] = (s_red[2] + s_red[7]) + bgw * bg[2];
    o_inv[ray] = s_red[4] + s_red[9];
  }
}

extern "C" void kernel_launch(void* const* d_in, const int* in_sizes, int n_in,
                              void* d_out, int out_size, void* d_ws, size_t ws_size,
                              hipStream_t stream) {
  const float* h   = (const float*)d_in[1];
  const float* w   = (const float*)d_in[2];
  const float* K   = (const float*)d_in[3];
  const float* E   = (const float*)d_in[4];
  const float* bg  = (const float*)d_in[5];
  const float* Wd1 = (const float*)d_in[6];
  const float* bd1 = (const float*)d_in[7];
  const float* Wd2 = (const float*)d_in[8];
  const float* bd2 = (const float*)d_in[9];
  const float* Wc1 = (const float*)d_in[10];
  const float* bc1 = (const float*)d_in[11];
  const float* Wc2 = (const float*)d_in[12];
  const float* bc2 = (const float*)d_in[13];
  const int n_rays = in_sizes[1];

  nerf_fwd<<<n_rays, NT, 0, stream>>>(h, w, K, E, bg, Wd1, bd1, Wd2, bd2,
                                      Wc1, bc1, Wc2, bc2,
                                      (float*)d_out, n_rays);
}

// Round 11
// 185.006 us; speedup vs baseline: 22.0958x; 1.0438x over previous
//
#include <hip/hip_runtime.h>
#include <stdint.h>

#define SC 192      // coarse samples (128 + 64)
#define SF 128      // fine (importance) samples
#define NT 128      // threads per block = 2 waves

// LDS weight-table offsets (floats)
#define WD1   0     // 96  (3x32 row-major)
#define BD1   96    // 32
#define WD2   128   // 32
#define BD2   160   // 1 (+3 pad)
#define BC1   164   // 32
#define WC2   196   // 96 (32x3)
#define BC2   292   // 3 (+1 pad)
#define WC1T  296   // 96 = Wc1 rows 32..34 (dir rows)
#define HPK   392   // 32x8 packed per-hidden: [Wd1r0,Wd1r1,Wd1r2,bd1, Wd2,pad,pad,pad]
#define SWTOT (392 + 256)

#define HSTRIDE 40  // ushort stride for H rows (16B-aligned frags; 80B row stride -> ≤2-way conflicts, free)
#define RGBS 4      // s_rgb stride (conflicts at 4 measured negligible; LDS size matters more)

using short8 = __attribute__((ext_vector_type(8))) short;
using f32x4  = __attribute__((ext_vector_type(4))) float;

// z_log coarse grid
__device__ __forceinline__ float zlog_c(int t) {
  return (t < 128) ? (-1.0f + (float)t * 0.0078125f)
                   : ((float)(t - 128) * 0.015625f);
}
__device__ __forceinline__ float delta_c(int t) {
  if (t >= SC - 1) return 0.0f;
  return zlog_c(t + 1) - zlog_c(t);
}

__device__ __forceinline__ float fast_rcp(float x) { return __builtin_amdgcn_rcpf(x); }
__device__ __forceinline__ float fast_rsq(float x) { return __builtin_amdgcn_rsqf(x); }
__device__ __forceinline__ float exp10_f(float x) { return __expf(x * 2.30258509299f); }
__device__ __forceinline__ float softplus_f(float x) {
  return fmaxf(x, 0.0f) + __logf(1.0f + __expf(-fabsf(x)));
}

// bf16 RTN-even helpers
__device__ __forceinline__ unsigned short f2bf(float f) {
  uint32_t u = __float_as_uint(f);
  return (unsigned short)((u + 0x7fffu + ((u >> 16) & 1u)) >> 16);
}
__device__ __forceinline__ float bf2f(unsigned short h) {
  return __uint_as_float(((uint32_t)h) << 16);
}

__device__ __forceinline__ float4 ldsf4(const float* p) { return *(const float4*)p; }

// JAX threefry2x32 with key = (0, 42)
__device__ __forceinline__ void threefry2x32_k42(uint32_t& x0, uint32_t& x1) {
  const uint32_t ks0 = 0u, ks1 = 42u;
  const uint32_t ks2 = ks0 ^ ks1 ^ 0x1BD11BDAu;
  const uint32_t ks[3] = {ks0, ks1, ks2};
  const int rot[2][4] = {{13, 15, 26, 6}, {17, 29, 16, 24}};
  x0 += ks[0];
  x1 += ks[1];
#pragma unroll
  for (int i = 0; i < 5; ++i) {
#pragma unroll
    for (int j = 0; j < 4; ++j) {
      x0 += x1;
      const int r = rot[i & 1][j];
      x1 = (x1 << r) | (x1 >> (32 - r));
      x1 ^= x0;
    }
    x0 += ks[(i + 1) % 3];
    x1 += ks[(i + 2) % 3] + (uint32_t)(i + 1);
  }
}

__device__ __forceinline__ float wave_scan_mul(float v, int lane) {
#pragma unroll
  for (int d = 1; d < 64; d <<= 1) {
    float o = __shfl_up(v, d, 64);
    if (lane >= d) v *= o;
  }
  return v;
}
__device__ __forceinline__ float wave_scan_add(float v, int lane) {
#pragma unroll
  for (int d = 1; d < 64; d <<= 1) {
    float o = __shfl_up(v, d, 64);
    if (lane >= d) v += o;
  }
  return v;
}

// coarse density: float4 LDS reads; unroll 2 for ds_read ILP
__device__ __forceinline__ float density_sigma_lds(
    float px, float py, float pz, const float* sw, float bd2v) {
  float acc = bd2v;
#pragma unroll 2
  for (int c = 0; c < 8; ++c) {
    const int k4 = c * 4;
    const float4 w0 = ldsf4(sw + WD1 + k4);
    const float4 w1 = ldsf4(sw + WD1 + 32 + k4);
    const float4 w2 = ldsf4(sw + WD1 + 64 + k4);
    const float4 b  = ldsf4(sw + BD1 + k4);
    const float4 wd = ldsf4(sw + WD2 + k4);
    float v;
    v = b.x + px * w0.x + py * w1.x + pz * w2.x; acc += fmaxf(v, 0.0f) * wd.x;
    v = b.y + px * w0.y + py * w1.y + pz * w2.y; acc += fmaxf(v, 0.0f) * wd.y;
    v = b.z + px * w0.z + py * w1.z + pz * w2.z; acc += fmaxf(v, 0.0f) * wd.z;
    v = b.w + px * w0.w + py * w1.w + pz * w2.w; acc += fmaxf(v, 0.0f) * wd.w;
  }
  return softplus_f(acc);
}

__global__ __launch_bounds__(NT) void nerf_fwd(
    const float* __restrict__ hh, const float* __restrict__ ww,
    const float* __restrict__ K, const float* __restrict__ E,
    const float* __restrict__ bg,
    const float* __restrict__ Wd1, const float* __restrict__ bd1,
    const float* __restrict__ Wd2, const float* __restrict__ bd2,
    const float* __restrict__ Wc1, const float* __restrict__ bc1,
    const float* __restrict__ Wc2, const float* __restrict__ bc2,
    float* __restrict__ out, int n_rays) {
  const int ray = blockIdx.x;
  const int t = threadIdx.x;
  const int lane = t & 63;
  const int wv = t >> 6;   // 0 or 1
  const int quad = lane >> 4;

  __shared__ float sw[SWTOT];
  // phase-union: coarse {s_w, s_cdf} then fine H (bf16). Barrier separates lifetimes.
  __shared__ __align__(16) unsigned char u_buf[SF * HSTRIDE * 2];  // 10240 B
  float* const s_w   = (float*)u_buf;            // 192 floats (coarse)
  float* const s_cdf = (float*)(u_buf + 768);    // 192 floats (coarse)
  unsigned short* const s_hhi = (unsigned short*)u_buf;  // 128 x HSTRIDE (fine)
  __shared__ float s_rgb[SF * RGBS];
  __shared__ float s_zlf[SF];
  __shared__ float s_tot[8];
  __shared__ float s_red[16];

  // ---- stage small weight tables into LDS (once per block) ----
  for (int i = t; i < 96; i += NT)   sw[WD1 + i] = Wd1[i];
  for (int i = t; i < 32; i += NT) { sw[BD1 + i] = bd1[i]; sw[WD2 + i] = Wd2[i]; sw[BC1 + i] = bc1[i]; }
  if (t == 0) sw[BD2] = bd2[0];
  for (int i = t; i < 96; i += NT) { sw[WC2 + i] = Wc2[i]; sw[WC1T + i] = Wc1[32 * 32 + i]; }
  for (int i = t; i < 3; i += NT)    sw[BC2 + i] = bc2[i];
  if (t < 32) {  // packed per-hidden table for fine density
    sw[HPK + t * 8 + 0] = Wd1[t];
    sw[HPK + t * 8 + 1] = Wd1[32 + t];
    sw[HPK + t * 8 + 2] = Wd1[64 + t];
    sw[HPK + t * 8 + 3] = bd1[t];
    sw[HPK + t * 8 + 4] = Wd2[t];
  }

  // ---- ray setup (block-uniform) ----
  const float k00 = K[0], k01 = K[1], k02 = K[2];
  const float k10 = K[3], k11 = K[4], k12 = K[5];
  const float k20 = K[6], k21 = K[7], k22 = K[8];
  const float det = k00 * (k11 * k22 - k12 * k21)
                  - k01 * (k10 * k22 - k12 * k20)
                  + k02 * (k10 * k21 - k11 * k20);
  const float id = 1.0f / det;
  const float i00 =  (k11 * k22 - k12 * k21) * id;
  const float i01 = -(k01 * k22 - k02 * k21) * id;
  const float i02 =  (k01 * k12 - k02 * k11) * id;
  const float i10 = -(k10 * k22 - k12 * k20) * id;
  const float i11 =  (k00 * k22 - k02 * k20) * id;
  const float i12 = -(k00 * k12 - k02 * k10) * id;
  const float i20 =  (k10 * k21 - k11 * k20) * id;
  const float i21 = -(k00 * k21 - k01 * k20) * id;
  const float i22 =  (k00 * k11 - k01 * k10) * id;

  const float dwx = ww[ray] + 0.5f;
  const float dwy = hh[ray] + 0.5f;
  const float cx = i00 * dwx + i01 * dwy + i02;
  const float cy = i10 * dwx + i11 * dwy + i12;
  const float cz = i20 * dwx + i21 * dwy + i22;
  const float* Er = E + (size_t)ray * 16;
  const float ox = Er[3], oy = Er[7], oz = Er[11];
  const float dx = Er[0] * cx + Er[1] * cy + Er[2] * cz;
  const float dy = Er[4] * cx + Er[5] * cy + Er[6] * cz;
  const float dz = Er[8] * cx + Er[9] * cy + Er[10] * cz;
  const float inv_nrm = fast_rsq(dx * dx + dy * dy + dz * dz);
  const float ndx = dx * inv_nrm, ndy = dy * inv_nrm, ndz = dz * inv_nrm;

  __syncthreads();   // weights staged

  // ---- coarse pass ----
  const float bd2v = sw[BD2];
  float a0, v0, a1e = 0.0f, v1e = 1.0f;
  {
    const float z = exp10_f(zlog_c(t));
    float px = ox + dx * z, py = oy + dy * z, pz = oz + dz * z;
    const float dist = sqrtf(px * px + py * py + pz * pz);
    if (dist > 1.0f) {
      const float invd = fast_rcp(dist);
      const float sc = (2.0f - invd) * invd;
      px *= sc; py *= sc; pz *= sc;
    }
    const float sig = density_sigma_lds(px, py, pz, sw, bd2v);
    v0 = __expf(-sig * delta_c(t));
    a0 = 1.0f - v0;
  }
  if (wv == 0) {
    const int e = 128 + t;
    const float z = exp10_f(zlog_c(e));
    float px = ox + dx * z, py = oy + dy * z, pz = oz + dz * z;
    const float dist = sqrtf(px * px + py * py + pz * pz);
    if (dist > 1.0f) {
      const float invd = fast_rcp(dist);
      const float sc = (2.0f - invd) * invd;
      px *= sc; py *= sc; pz *= sc;
    }
    const float sig = density_sigma_lds(px, py, pz, sw, bd2v);
    v1e = __expf(-sig * delta_c(e));
    a1e = 1.0f - v1e;
  }

  // parallel cumprod of (1-alpha)
  float i0 = wave_scan_mul(v0, lane);
  float i1 = 1.0f;
  if (wv == 0) i1 = wave_scan_mul(v1e, lane);
  if (lane == 63) s_tot[wv] = i0;
  if (wv == 0 && lane == 63) s_tot[2] = i1;
  __syncthreads();
  {
    const float preC1 = s_tot[0];
    const float preC2 = s_tot[0] * s_tot[1];
    float e0x = __shfl_up(i0, 1, 64); if (lane == 0) e0x = 1.0f;
    s_w[t] = a0 * e0x * (wv ? preC1 : 1.0f);
    if (wv == 0) {
      float e1x = __shfl_up(i1, 1, 64); if (lane == 0) e1x = 1.0f;
      s_w[128 + t] = a1e * e1x * preC2;
    }
  }
  __syncthreads();

  // reweight
  float wre0, wre1 = 0.0f;
  {
    const float wm = (t > 0) ? s_w[t - 1] : 0.0f;
    const float w0 = s_w[t];
    const float wp = s_w[t + 1];
    wre0 = 0.5f * (fmaxf(wm, w0) + fmaxf(w0, wp)) + (0.02f / 192.0f);
    wre0 *= (t < 128) ? (128.0f / 192.0f) : (64.0f / 192.0f);
  }
  if (wv == 0) {
    const int e = 128 + t;
    const float wm = s_w[e - 1];
    const float w0 = s_w[e];
    const float wp = (e < SC - 1) ? s_w[e + 1] : 0.0f;
    wre1 = 0.5f * (fmaxf(wm, w0) + fmaxf(w0, wp)) + (0.02f / 192.0f);
    wre1 *= (64.0f / 192.0f);
  }

  // parallel cumsum -> normalized CDF
  float s0 = wave_scan_add(wre0, lane);
  float s1 = 0.0f;
  if (wv == 0) s1 = wave_scan_add(wre1, lane);
  if (lane == 63) s_tot[4 + wv] = s0;
  if (wv == 0 && lane == 63) s_tot[6] = s1;
  __syncthreads();
  {
    const float T0 = s_tot[4], T1 = s_tot[5], T2 = s_tot[6];
    const float inv_total = fast_rcp(T0 + T1 + T2);
    s_cdf[t] = (s0 + (wv ? T0 : 0.0f)) * inv_total;
    if (wv == 0) s_cdf[128 + t] = (s1 + T0 + T1) * inv_total;
  }
  __syncthreads();

  // ---- importance sampling ----
  float zlf, zf;
  {
    const uint32_t total = (uint32_t)n_rays * 128u;
    const uint32_t halfc = total >> 1;
    const uint32_t j = (uint32_t)ray * 128u + (uint32_t)t;
    uint32_t x0, x1;
    const bool first = (j < halfc);
    if (first) { x0 = j; x1 = j + halfc; } else { x0 = j - halfc; x1 = j; }
    threefry2x32_k42(x0, x1);
    const uint32_t bits = first ? x0 : x1;
    const float fr = __uint_as_float((bits >> 9) | 0x3f800000u) - 1.0f;

    float u = (float)t * 0.0078125f + fr * 0.0078125f;
    u = u * (s_cdf[190] - s_cdf[1]) + s_cdf[1];

    int lo = 0, hi = 189;
    while (lo < hi) {
      const int mid = (lo + hi) >> 1;
      if (s_cdf[1 + mid] <= u) lo = mid + 1; else hi = mid;
    }
    const int inds = lo + 1;
    const float cb = s_cdf[inds - 1], ca = s_cdf[inds];
    const float tt = (u - cb) * fast_rcp(ca - cb);
    const float zb = 0.5f * (zlog_c(inds - 1) + zlog_c(inds));
    const float za = 0.5f * (zlog_c(inds) + zlog_c(inds + 1));
    zlf = zb + (za - zb) * tt;
    s_zlf[t] = zlf;
    zf = exp10_f(zlf);
  }
  __syncthreads();   // last s_cdf read above — union area now free for s_hhi

  // ---- fine density per-thread; h -> LDS as bf16 (hi only) ----
  float sigf;
  {
    float px = ox + dx * zf, py = oy + dy * zf, pz = oz + dz * zf;
    const float dist = sqrtf(px * px + py * py + pz * pz);
    if (dist > 1.0f) {
      const float invd = fast_rcp(dist);
      const float sc = (2.0f - invd) * invd;
      px *= sc; py *= sc; pz *= sc;
    }
    float sig_acc = bd2v;
#pragma unroll
    for (int c = 0; c < 4; ++c) {
      uint32_t hwv[4];
#pragma unroll
      for (int j2 = 0; j2 < 4; ++j2) {
        uint32_t hp = 0;
#pragma unroll
        for (int b = 0; b < 2; ++b) {
          const int i = c * 8 + j2 * 2 + b;
          const float4 hpk = ldsf4(sw + HPK + i * 8);
          const float wd2i = sw[HPK + i * 8 + 4];
          float hv = hpk.w + px * hpk.x + py * hpk.y + pz * hpk.z;
          hv = fmaxf(hv, 0.0f);
          sig_acc += hv * wd2i;
          hp |= ((uint32_t)f2bf(hv)) << (16 * b);
        }
        hwv[j2] = hp;
      }
      *(uint4*)(s_hhi + t * HSTRIDE + c * 8) = make_uint4(hwv[0], hwv[1], hwv[2], hwv[3]);
    }
    sigf = softplus_f(sig_acc);
  }
  __syncthreads();   // h staged for MFMA

  // ---- fine color via MFMA: a1^T[32 x 128] = Wc1^T . H^T (W hi+lo regs, H hi) ----
  {
    // pack Wc1[0:32][:] A-frags in registers at point of use (L2-hit loads, once/wave)
    short8 Wfr[4];  // [hi0, lo0, hi1, lo1]
#pragma unroll
    for (int nt = 0; nt < 2; ++nt) {
      const int n_s = nt * 16 + (lane & 15);
      uint32_t hwv[4], lwv[4];
#pragma unroll
      for (int j2 = 0; j2 < 4; ++j2) {
        uint32_t hp = 0, lp = 0;
#pragma unroll
        for (int b = 0; b < 2; ++b) {
          const int k = quad * 8 + j2 * 2 + b;
          const float wval = Wc1[k * 32 + n_s];
          const unsigned short hb = f2bf(wval);
          const unsigned short lb = f2bf(wval - bf2f(hb));
          hp |= ((uint32_t)hb) << (16 * b);
          lp |= ((uint32_t)lb) << (16 * b);
        }
        hwv[j2] = hp; lwv[j2] = lp;
      }
      uint4 hq = make_uint4(hwv[0], hwv[1], hwv[2], hwv[3]);
      uint4 lq = make_uint4(lwv[0], lwv[1], lwv[2], lwv[3]);
      Wfr[nt * 2 + 0] = *(short8*)&hq;
      Wfr[nt * 2 + 1] = *(short8*)&lq;
    }

    // per-lane n-values: n = nt*16 + quad*4 + r
    float dvv[2][4], w2v[2][4][3];
#pragma unroll
    for (int nt = 0; nt < 2; ++nt)
#pragma unroll
      for (int r = 0; r < 4; ++r) {
        const int n = nt * 16 + quad * 4 + r;
        dvv[nt][r] = sw[BC1 + n] + ndx * sw[WC1T + n]
                   + ndy * sw[WC1T + 32 + n] + ndz * sw[WC1T + 64 + n];
#pragma unroll
        for (int c = 0; c < 3; ++c) w2v[nt][r][c] = sw[WC2 + n * 3 + c];
      }

#pragma unroll
    for (int mt = 0; mt < 4; ++mt) {
      const int sbase = wv * 64 + mt * 16;
      const int srow = sbase + (lane & 15);
      const short8 Hhi = *(const short8*)(s_hhi + srow * HSTRIDE + quad * 8);

      f32x4 acc0 = {0.f, 0.f, 0.f, 0.f}, acc1 = {0.f, 0.f, 0.f, 0.f};
      acc0 = __builtin_amdgcn_mfma_f32_16x16x32_bf16(Wfr[0], Hhi, acc0, 0, 0, 0);
      acc0 = __builtin_amdgcn_mfma_f32_16x16x32_bf16(Wfr[1], Hhi, acc0, 0, 0, 0);
      acc1 = __builtin_amdgcn_mfma_f32_16x16x32_bf16(Wfr[2], Hhi, acc1, 0, 0, 0);
      acc1 = __builtin_amdgcn_mfma_f32_16x16x32_bf16(Wfr[3], Hhi, acc1, 0, 0, 0);

      // layer2 partial over this lane's 8 n-values (in-register)
      float pc0 = 0.f, pc1 = 0.f, pc2 = 0.f;
#pragma unroll
      for (int r = 0; r < 4; ++r) {
        const float av0 = fmaxf(acc0[r] + dvv[0][r], 0.0f);
        const float av1 = fmaxf(acc1[r] + dvv[1][r], 0.0f);
        pc0 += av0 * w2v[0][r][0] + av1 * w2v[1][r][0];
        pc1 += av0 * w2v[0][r][1] + av1 * w2v[1][r][1];
        pc2 += av0 * w2v[0][r][2] + av1 * w2v[1][r][2];
      }
      // reduce over the 4 quads
#pragma unroll
      for (int mask = 16; mask < 64; mask <<= 1) {
        pc0 += __shfl_xor(pc0, mask, 64);
        pc1 += __shfl_xor(pc1, mask, 64);
        pc2 += __shfl_xor(pc2, mask, 64);
      }
      const int cidx = lane >> 4;
      const float oc = (cidx == 0) ? pc0 : ((cidx == 1) ? pc1 : pc2);
      if (lane < 48) {
        const int s = sbase + (lane & 15);
        const float o = oc + sw[BC2 + cidx];
        s_rgb[s * RGBS + cidx] = fast_rcp(1.0f + __expf(-o));
      }
    }
  }

  // ---- fine alpha + parallel cumprod over 128 ----
  const float deltaf = (t < SF - 1) ? (s_zlf[t + 1] - zlf) : 0.0f;
  const float vf = __expf(-sigf * deltaf);
  const float af = 1.0f - vf;
  float fi = wave_scan_mul(vf, lane);
  if (lane == 63) s_tot[wv] = fi;
  __syncthreads();   // also makes s_rgb visible
  float efx = __shfl_up(fi, 1, 64); if (lane == 0) efx = 1.0f;
  const float wf = af * efx * (wv ? s_tot[0] : 1.0f);

  // ---- outputs ----
  float* o_img = out;
  float* o_w   = out + (size_t)n_rays * 3;
  float* o_z   = out + (size_t)n_rays * (3 + 128);
  float* o_inv = out + (size_t)n_rays * (3 + 256);

  o_w[(size_t)ray * 128 + t] = wf;
  o_z[(size_t)ray * 128 + t] = (zlf + 1.0f) * 0.5f;

  float r0 = wf * s_rgb[t * RGBS + 0];
  float r1 = wf * s_rgb[t * RGBS + 1];
  float r2 = wf * s_rgb[t * RGBS + 2];
  float r3 = wf, r4 = wf * fast_rcp(zf);
#pragma unroll
  for (int d = 32; d > 0; d >>= 1) {
    r0 += __shfl_down(r0, d, 64);
    r1 += __shfl_down(r1, d, 64);
    r2 += __shfl_down(r2, d, 64);
    r3 += __shfl_down(r3, d, 64);
    r4 += __shfl_down(r4, d, 64);
  }
  if (lane == 0) {
    float* p = &s_red[wv * 5];
    p[0] = r0; p[1] = r1; p[2] = r2; p[3] = r3; p[4] = r4;
  }
  __syncthreads();
  if (t == 0) {
    const float accw = s_red[3] + s_red[8];
    const float bgw = 1.0f - accw;
    o_img[(size_t)ray * 3 + 0] = (s_red[0] + s_red[5]) + bgw * bg[0];
    o_img[(size_t)ray * 3 + 1] = (s_red[1] + s_red[6]) + bgw * bg[1];
    o_img[(size_t)ray * 3 + 2] = (s_red[2] + s_red[7]) + bgw * bg[2];
    o_inv[ray] = s_red[4] + s_red[9];
  }
}

extern "C" void kernel_launch(void* const* d_in, const int* in_sizes, int n_in,
                              void* d_out, int out_size, void* d_ws, size_t ws_size,
                              hipStream_t stream) {
  const float* h   = (const float*)d_in[1];
  const float* w   = (const float*)d_in[2];
  const float* K   = (const float*)d_in[3];
  const float* E   = (const float*)d_in[4];
  const float* bg  = (const float*)d_in[5];
  const float* Wd1 = (const float*)d_in[6];
  const float* bd1 = (const float*)d_in[7];
  const float* Wd2 = (const float*)d_in[8];
  const float* bd2 = (const float*)d_in[9];
  const float* Wc1 = (const float*)d_in[10];
  const float* bc1 = (const float*)d_in[11];
  const float* Wc2 = (const float*)d_in[12];
  const float* bc2 = (const float*)d_in[13];
  const int n_rays = in_sizes[1];

  nerf_fwd<<<n_rays, NT, 0, stream>>>(h, w, K, E, bg, Wd1, bd1, Wd2, bd2,
                                      Wc1, bc1, Wc2, bc2,
                                      (float*)d_out, n_rays);
}

// Round 12
// 180.146 us; speedup vs baseline: 22.6920x; 1.0270x over previous
//
#include <hip/hip_runtime.h>
#include <stdint.h>

#define SC 192      // coarse samples (128 + 64)
#define SF 128      // fine (importance) samples
#define NT 128      // threads per block = 2 waves

// LDS weight-table offsets (floats)
#define WD1   0     // 96  (3x32 row-major)
#define BD1   96    // 32
#define WD2   128   // 32
#define BD2   160   // 1 (+3 pad)
#define BC1   164   // 32
#define WC2   196   // 96 (32x3)
#define BC2   292   // 3 (+1 pad)
#define WC1T  296   // 96 = Wc1 rows 32..34 (dir rows)
#define HPK   392   // 32x8 packed per-hidden: [Wd1r0,Wd1r1,Wd1r2,bd1, Wd2,pad,pad,pad]
#define SWTOT (392 + 256)   // 648 floats (16B-multiple)

#define WS_FRAG_OFF 4096    // byte offset of Wc1 frag area in d_ws
#define WS_NEED     8192    // bytes of d_ws we use

#define HSTRIDE 40  // ushort stride for H rows
#define RGBS 4      // s_rgb stride

using short8 = __attribute__((ext_vector_type(8))) short;
using f32x4  = __attribute__((ext_vector_type(4))) float;

// z_log coarse grid
__device__ __forceinline__ float zlog_c(int t) {
  return (t < 128) ? (-1.0f + (float)t * 0.0078125f)
                   : ((float)(t - 128) * 0.015625f);
}
__device__ __forceinline__ float delta_c(int t) {
  if (t >= SC - 1) return 0.0f;
  return zlog_c(t + 1) - zlog_c(t);
}

__device__ __forceinline__ float fast_rcp(float x) { return __builtin_amdgcn_rcpf(x); }
__device__ __forceinline__ float fast_rsq(float x) { return __builtin_amdgcn_rsqf(x); }
__device__ __forceinline__ float exp10_f(float x) { return __expf(x * 2.30258509299f); }
__device__ __forceinline__ float softplus_f(float x) {
  return fmaxf(x, 0.0f) + __logf(1.0f + __expf(-fabsf(x)));
}

// bf16 RTN-even helpers
__device__ __forceinline__ unsigned short f2bf(float f) {
  uint32_t u = __float_as_uint(f);
  return (unsigned short)((u + 0x7fffu + ((u >> 16) & 1u)) >> 16);
}
__device__ __forceinline__ float bf2f(unsigned short h) {
  return __uint_as_float(((uint32_t)h) << 16);
}

__device__ __forceinline__ float4 ldsf4(const float* p) { return *(const float4*)p; }

// JAX threefry2x32 with key = (0, 42)
__device__ __forceinline__ void threefry2x32_k42(uint32_t& x0, uint32_t& x1) {
  const uint32_t ks0 = 0u, ks1 = 42u;
  const uint32_t ks2 = ks0 ^ ks1 ^ 0x1BD11BDAu;
  const uint32_t ks[3] = {ks0, ks1, ks2};
  const int rot[2][4] = {{13, 15, 26, 6}, {17, 29, 16, 24}};
  x0 += ks[0];
  x1 += ks[1];
#pragma unroll
  for (int i = 0; i < 5; ++i) {
#pragma unroll
    for (int j = 0; j < 4; ++j) {
      x0 += x1;
      const int r = rot[i & 1][j];
      x1 = (x1 << r) | (x1 >> (32 - r));
      x1 ^= x0;
    }
    x0 += ks[(i + 1) % 3];
    x1 += ks[(i + 2) % 3] + (uint32_t)(i + 1);
  }
}

__device__ __forceinline__ float wave_scan_mul(float v, int lane) {
#pragma unroll
  for (int d = 1; d < 64; d <<= 1) {
    float o = __shfl_up(v, d, 64);
    if (lane >= d) v *= o;
  }
  return v;
}
__device__ __forceinline__ float wave_scan_add(float v, int lane) {
#pragma unroll
  for (int d = 1; d < 64; d <<= 1) {
    float o = __shfl_up(v, d, 64);
    if (lane >= d) v += o;
  }
  return v;
}

// coarse density: float4 LDS reads; unroll 2 for ds_read ILP
__device__ __forceinline__ float density_sigma_lds(
    float px, float py, float pz, const float* sw, float bd2v) {
  float acc = bd2v;
#pragma unroll 2
  for (int c = 0; c < 8; ++c) {
    const int k4 = c * 4;
    const float4 w0 = ldsf4(sw + WD1 + k4);
    const float4 w1 = ldsf4(sw + WD1 + 32 + k4);
    const float4 w2 = ldsf4(sw + WD1 + 64 + k4);
    const float4 b  = ldsf4(sw + BD1 + k4);
    const float4 wd = ldsf4(sw + WD2 + k4);
    float v;
    v = b.x + px * w0.x + py * w1.x + pz * w2.x; acc += fmaxf(v, 0.0f) * wd.x;
    v = b.y + px * w0.y + py * w1.y + pz * w2.y; acc += fmaxf(v, 0.0f) * wd.y;
    v = b.z + px * w0.z + py * w1.z + pz * w2.z; acc += fmaxf(v, 0.0f) * wd.z;
    v = b.w + px * w0.w + py * w1.w + pz * w2.w; acc += fmaxf(v, 0.0f) * wd.w;
  }
  return softplus_f(acc);
}

// ---- pre-pack kernel: build LDS weight image + Wc1 MFMA frags in d_ws ----
// Identical bits for every block of the main kernel — compute ONCE per launch.
__global__ __launch_bounds__(NT) void pack_weights(
    const float* __restrict__ Wd1, const float* __restrict__ bd1,
    const float* __restrict__ Wd2, const float* __restrict__ bd2,
    const float* __restrict__ Wc1, const float* __restrict__ bc1,
    const float* __restrict__ Wc2, const float* __restrict__ bc2,
    float* __restrict__ wsf) {
  const int t = threadIdx.x;
  for (int i = t; i < 96; i += NT)   wsf[WD1 + i] = Wd1[i];
  for (int i = t; i < 32; i += NT) { wsf[BD1 + i] = bd1[i]; wsf[WD2 + i] = Wd2[i]; wsf[BC1 + i] = bc1[i]; }
  if (t == 0) wsf[BD2] = bd2[0];
  for (int i = t; i < 96; i += NT) { wsf[WC2 + i] = Wc2[i]; wsf[WC1T + i] = Wc1[32 * 32 + i]; }
  for (int i = t; i < 3; i += NT)    wsf[BC2 + i] = bc2[i];
  if (t < 32) {
    wsf[HPK + t * 8 + 0] = Wd1[t];
    wsf[HPK + t * 8 + 1] = Wd1[32 + t];
    wsf[HPK + t * 8 + 2] = Wd1[64 + t];
    wsf[HPK + t * 8 + 3] = bd1[t];
    wsf[HPK + t * 8 + 4] = Wd2[t];
    wsf[HPK + t * 8 + 5] = 0.0f;
    wsf[HPK + t * 8 + 6] = 0.0f;
    wsf[HPK + t * 8 + 7] = 0.0f;
  }
  // Wc1[0:32][:] A-frags (hi/lo): frag[lane*4 + nt*2 + part]
  if (t < 64) {
    const int lane_s = t, q_s = lane_s >> 4;
    uint4* frag = (uint4*)((char*)wsf + WS_FRAG_OFF);
#pragma unroll
    for (int nt = 0; nt < 2; ++nt) {
      const int n_s = nt * 16 + (lane_s & 15);
      uint32_t hwv[4], lwv[4];
#pragma unroll
      for (int j2 = 0; j2 < 4; ++j2) {
        uint32_t hp = 0, lp = 0;
#pragma unroll
        for (int b = 0; b < 2; ++b) {
          const int k = q_s * 8 + j2 * 2 + b;
          const float wval = Wc1[k * 32 + n_s];
          const unsigned short hb = f2bf(wval);
          const unsigned short lb = f2bf(wval - bf2f(hb));
          hp |= ((uint32_t)hb) << (16 * b);
          lp |= ((uint32_t)lb) << (16 * b);
        }
        hwv[j2] = hp; lwv[j2] = lp;
      }
      frag[lane_s * 4 + nt * 2 + 0] = make_uint4(hwv[0], hwv[1], hwv[2], hwv[3]);
      frag[lane_s * 4 + nt * 2 + 1] = make_uint4(lwv[0], lwv[1], lwv[2], lwv[3]);
    }
  }
}

template <bool USE_WS>
__global__ __launch_bounds__(NT) void nerf_fwd(
    const float* __restrict__ hh, const float* __restrict__ ww,
    const float* __restrict__ K, const float* __restrict__ E,
    const float* __restrict__ bg,
    const float* __restrict__ Wd1, const float* __restrict__ bd1,
    const float* __restrict__ Wd2, const float* __restrict__ bd2,
    const float* __restrict__ Wc1, const float* __restrict__ bc1,
    const float* __restrict__ Wc2, const float* __restrict__ bc2,
    const float* __restrict__ wsf,
    float* __restrict__ out, int n_rays) {
  const int ray = blockIdx.x;
  const int t = threadIdx.x;
  const int lane = t & 63;
  const int wv = t >> 6;   // 0 or 1
  const int quad = lane >> 4;

  __shared__ __align__(16) float sw[SWTOT];
  // phase-union: coarse {s_w, s_cdf} then fine H (bf16)
  __shared__ __align__(16) unsigned char u_buf[SF * HSTRIDE * 2];  // 10240 B
  float* const s_w   = (float*)u_buf;
  float* const s_cdf = (float*)(u_buf + 768);
  unsigned short* const s_hhi = (unsigned short*)u_buf;
  __shared__ float s_rgb[SF * RGBS];
  __shared__ float s_zlf[SF];
  __shared__ float s_tot[8];
  __shared__ float s_red[16];

  // ---- stage weight image into LDS ----
  if constexpr (USE_WS) {
    const float4* wsrc = (const float4*)wsf;
    float4* sdst = (float4*)sw;
    for (int i = t; i < SWTOT / 4; i += NT) sdst[i] = wsrc[i];
  } else {
    for (int i = t; i < 96; i += NT)   sw[WD1 + i] = Wd1[i];
    for (int i = t; i < 32; i += NT) { sw[BD1 + i] = bd1[i]; sw[WD2 + i] = Wd2[i]; sw[BC1 + i] = bc1[i]; }
    if (t == 0) sw[BD2] = bd2[0];
    for (int i = t; i < 96; i += NT) { sw[WC2 + i] = Wc2[i]; sw[WC1T + i] = Wc1[32 * 32 + i]; }
    for (int i = t; i < 3; i += NT)    sw[BC2 + i] = bc2[i];
    if (t < 32) {
      sw[HPK + t * 8 + 0] = Wd1[t];
      sw[HPK + t * 8 + 1] = Wd1[32 + t];
      sw[HPK + t * 8 + 2] = Wd1[64 + t];
      sw[HPK + t * 8 + 3] = bd1[t];
      sw[HPK + t * 8 + 4] = Wd2[t];
    }
  }

  // ---- ray setup (block-uniform) ----
  const float k00 = K[0], k01 = K[1], k02 = K[2];
  const float k10 = K[3], k11 = K[4], k12 = K[5];
  const float k20 = K[6], k21 = K[7], k22 = K[8];
  const float det = k00 * (k11 * k22 - k12 * k21)
                  - k01 * (k10 * k22 - k12 * k20)
                  + k02 * (k10 * k21 - k11 * k20);
  const float id = 1.0f / det;
  const float i00 =  (k11 * k22 - k12 * k21) * id;
  const float i01 = -(k01 * k22 - k02 * k21) * id;
  const float i02 =  (k01 * k12 - k02 * k11) * id;
  const float i10 = -(k10 * k22 - k12 * k20) * id;
  const float i11 =  (k00 * k22 - k02 * k20) * id;
  const float i12 = -(k00 * k12 - k02 * k10) * id;
  const float i20 =  (k10 * k21 - k11 * k20) * id;
  const float i21 = -(k00 * k21 - k01 * k20) * id;
  const float i22 =  (k00 * k11 - k01 * k10) * id;

  const float dwx = ww[ray] + 0.5f;
  const float dwy = hh[ray] + 0.5f;
  const float cx = i00 * dwx + i01 * dwy + i02;
  const float cy = i10 * dwx + i11 * dwy + i12;
  const float cz = i20 * dwx + i21 * dwy + i22;
  const float* Er = E + (size_t)ray * 16;
  const float ox = Er[3], oy = Er[7], oz = Er[11];
  const float dx = Er[0] * cx + Er[1] * cy + Er[2] * cz;
  const float dy = Er[4] * cx + Er[5] * cy + Er[6] * cz;
  const float dz = Er[8] * cx + Er[9] * cy + Er[10] * cz;
  const float inv_nrm = fast_rsq(dx * dx + dy * dy + dz * dz);
  const float ndx = dx * inv_nrm, ndy = dy * inv_nrm, ndz = dz * inv_nrm;

  __syncthreads();   // weights staged

  // ---- coarse pass ----
  const float bd2v = sw[BD2];
  float a0, v0, a1e = 0.0f, v1e = 1.0f;
  {
    const float z = exp10_f(zlog_c(t));
    float px = ox + dx * z, py = oy + dy * z, pz = oz + dz * z;
    const float dist = sqrtf(px * px + py * py + pz * pz);
    if (dist > 1.0f) {
      const float invd = fast_rcp(dist);
      const float sc = (2.0f - invd) * invd;
      px *= sc; py *= sc; pz *= sc;
    }
    const float sig = density_sigma_lds(px, py, pz, sw, bd2v);
    v0 = __expf(-sig * delta_c(t));
    a0 = 1.0f - v0;
  }
  if (wv == 0) {
    const int e = 128 + t;
    const float z = exp10_f(zlog_c(e));
    float px = ox + dx * z, py = oy + dy * z, pz = oz + dz * z;
    const float dist = sqrtf(px * px + py * py + pz * pz);
    if (dist > 1.0f) {
      const float invd = fast_rcp(dist);
      const float sc = (2.0f - invd) * invd;
      px *= sc; py *= sc; pz *= sc;
    }
    const float sig = density_sigma_lds(px, py, pz, sw, bd2v);
    v1e = __expf(-sig * delta_c(e));
    a1e = 1.0f - v1e;
  }

  // parallel cumprod of (1-alpha)
  float i0 = wave_scan_mul(v0, lane);
  float i1 = 1.0f;
  if (wv == 0) i1 = wave_scan_mul(v1e, lane);
  if (lane == 63) s_tot[wv] = i0;
  if (wv == 0 && lane == 63) s_tot[2] = i1;
  __syncthreads();
  {
    const float preC1 = s_tot[0];
    const float preC2 = s_tot[0] * s_tot[1];
    float e0x = __shfl_up(i0, 1, 64); if (lane == 0) e0x = 1.0f;
    s_w[t] = a0 * e0x * (wv ? preC1 : 1.0f);
    if (wv == 0) {
      float e1x = __shfl_up(i1, 1, 64); if (lane == 0) e1x = 1.0f;
      s_w[128 + t] = a1e * e1x * preC2;
    }
  }
  __syncthreads();

  // reweight
  float wre0, wre1 = 0.0f;
  {
    const float wm = (t > 0) ? s_w[t - 1] : 0.0f;
    const float w0 = s_w[t];
    const float wp = s_w[t + 1];
    wre0 = 0.5f * (fmaxf(wm, w0) + fmaxf(w0, wp)) + (0.02f / 192.0f);
    wre0 *= (t < 128) ? (128.0f / 192.0f) : (64.0f / 192.0f);
  }
  if (wv == 0) {
    const int e = 128 + t;
    const float wm = s_w[e - 1];
    const float w0 = s_w[e];
    const float wp = (e < SC - 1) ? s_w[e + 1] : 0.0f;
    wre1 = 0.5f * (fmaxf(wm, w0) + fmaxf(w0, wp)) + (0.02f / 192.0f);
    wre1 *= (64.0f / 192.0f);
  }

  // parallel cumsum -> normalized CDF
  float s0 = wave_scan_add(wre0, lane);
  float s1 = 0.0f;
  if (wv == 0) s1 = wave_scan_add(wre1, lane);
  if (lane == 63) s_tot[4 + wv] = s0;
  if (wv == 0 && lane == 63) s_tot[6] = s1;
  __syncthreads();
  {
    const float T0 = s_tot[4], T1 = s_tot[5], T2 = s_tot[6];
    const float inv_total = fast_rcp(T0 + T1 + T2);
    s_cdf[t] = (s0 + (wv ? T0 : 0.0f)) * inv_total;
    if (wv == 0) s_cdf[128 + t] = (s1 + T0 + T1) * inv_total;
  }
  __syncthreads();

  // ---- importance sampling ----
  float zlf, zf;
  {
    const uint32_t total = (uint32_t)n_rays * 128u;
    const uint32_t halfc = total >> 1;
    const uint32_t j = (uint32_t)ray * 128u + (uint32_t)t;
    uint32_t x0, x1;
    const bool first = (j < halfc);
    if (first) { x0 = j; x1 = j + halfc; } else { x0 = j - halfc; x1 = j; }
    threefry2x32_k42(x0, x1);
    const uint32_t bits = first ? x0 : x1;
    const float fr = __uint_as_float((bits >> 9) | 0x3f800000u) - 1.0f;

    float u = (float)t * 0.0078125f + fr * 0.0078125f;
    u = u * (s_cdf[190] - s_cdf[1]) + s_cdf[1];

    int lo = 0, hi = 189;
    while (lo < hi) {
      const int mid = (lo + hi) >> 1;
      if (s_cdf[1 + mid] <= u) lo = mid + 1; else hi = mid;
    }
    const int inds = lo + 1;
    const float cb = s_cdf[inds - 1], ca = s_cdf[inds];
    const float tt = (u - cb) * fast_rcp(ca - cb);
    const float zb = 0.5f * (zlog_c(inds - 1) + zlog_c(inds));
    const float za = 0.5f * (zlog_c(inds) + zlog_c(inds + 1));
    zlf = zb + (za - zb) * tt;
    s_zlf[t] = zlf;
    zf = exp10_f(zlf);
  }
  __syncthreads();   // last s_cdf read above — union area now free for s_hhi

  // ---- Wc1 A-frags: precomputed (global, L2-hot) or packed in-wave ----
  short8 Wfr[4];  // [hi0, lo0, hi1, lo1]
  if constexpr (USE_WS) {
    const uint4* frag = (const uint4*)((const char*)wsf + WS_FRAG_OFF);
    uint4 q0 = frag[lane * 4 + 0];
    uint4 q1 = frag[lane * 4 + 1];
    uint4 q2 = frag[lane * 4 + 2];
    uint4 q3 = frag[lane * 4 + 3];
    Wfr[0] = *(short8*)&q0; Wfr[1] = *(short8*)&q1;
    Wfr[2] = *(short8*)&q2; Wfr[3] = *(short8*)&q3;
  } else {
#pragma unroll
    for (int nt = 0; nt < 2; ++nt) {
      const int n_s = nt * 16 + (lane & 15);
      uint32_t hwv[4], lwv[4];
#pragma unroll
      for (int j2 = 0; j2 < 4; ++j2) {
        uint32_t hp = 0, lp = 0;
#pragma unroll
        for (int b = 0; b < 2; ++b) {
          const int k = quad * 8 + j2 * 2 + b;
          const float wval = Wc1[k * 32 + n_s];
          const unsigned short hb = f2bf(wval);
          const unsigned short lb = f2bf(wval - bf2f(hb));
          hp |= ((uint32_t)hb) << (16 * b);
          lp |= ((uint32_t)lb) << (16 * b);
        }
        hwv[j2] = hp; lwv[j2] = lp;
      }
      uint4 hq = make_uint4(hwv[0], hwv[1], hwv[2], hwv[3]);
      uint4 lq = make_uint4(lwv[0], lwv[1], lwv[2], lwv[3]);
      Wfr[nt * 2 + 0] = *(short8*)&hq;
      Wfr[nt * 2 + 1] = *(short8*)&lq;
    }
  }

  // ---- fine density per-thread; h -> LDS as bf16 (hi only) ----
  float sigf;
  {
    float px = ox + dx * zf, py = oy + dy * zf, pz = oz + dz * zf;
    const float dist = sqrtf(px * px + py * py + pz * pz);
    if (dist > 1.0f) {
      const float invd = fast_rcp(dist);
      const float sc = (2.0f - invd) * invd;
      px *= sc; py *= sc; pz *= sc;
    }
    float sig_acc = bd2v;
#pragma unroll
    for (int c = 0; c < 4; ++c) {
      uint32_t hwv[4];
#pragma unroll
      for (int j2 = 0; j2 < 4; ++j2) {
        uint32_t hp = 0;
#pragma unroll
        for (int b = 0; b < 2; ++b) {
          const int i = c * 8 + j2 * 2 + b;
          const float4 hpk = ldsf4(sw + HPK + i * 8);
          const float wd2i = sw[HPK + i * 8 + 4];
          float hv = hpk.w + px * hpk.x + py * hpk.y + pz * hpk.z;
          hv = fmaxf(hv, 0.0f);
          sig_acc += hv * wd2i;
          hp |= ((uint32_t)f2bf(hv)) << (16 * b);
        }
        hwv[j2] = hp;
      }
      *(uint4*)(s_hhi + t * HSTRIDE + c * 8) = make_uint4(hwv[0], hwv[1], hwv[2], hwv[3]);
    }
    sigf = softplus_f(sig_acc);
  }
  __syncthreads();   // h staged for MFMA

  // ---- fine color via MFMA: a1^T[32 x 128] = Wc1^T . H^T (W hi+lo, H hi) ----
  {
    // per-lane n-values: n = nt*16 + quad*4 + r
    float dvv[2][4], w2v[2][4][3];
#pragma unroll
    for (int nt = 0; nt < 2; ++nt)
#pragma unroll
      for (int r = 0; r < 4; ++r) {
        const int n = nt * 16 + quad * 4 + r;
        dvv[nt][r] = sw[BC1 + n] + ndx * sw[WC1T + n]
                   + ndy * sw[WC1T + 32 + n] + ndz * sw[WC1T + 64 + n];
#pragma unroll
        for (int c = 0; c < 3; ++c) w2v[nt][r][c] = sw[WC2 + n * 3 + c];
      }

#pragma unroll
    for (int mt = 0; mt < 4; ++mt) {
      const int sbase = wv * 64 + mt * 16;
      const int srow = sbase + (lane & 15);
      const short8 Hhi = *(const short8*)(s_hhi + srow * HSTRIDE + quad * 8);

      f32x4 acc0 = {0.f, 0.f, 0.f, 0.f}, acc1 = {0.f, 0.f, 0.f, 0.f};
      acc0 = __builtin_amdgcn_mfma_f32_16x16x32_bf16(Wfr[0], Hhi, acc0, 0, 0, 0);
      acc0 = __builtin_amdgcn_mfma_f32_16x16x32_bf16(Wfr[1], Hhi, acc0, 0, 0, 0);
      acc1 = __builtin_amdgcn_mfma_f32_16x16x32_bf16(Wfr[2], Hhi, acc1, 0, 0, 0);
      acc1 = __builtin_amdgcn_mfma_f32_16x16x32_bf16(Wfr[3], Hhi, acc1, 0, 0, 0);

      // layer2 partial over this lane's 8 n-values
      float pc0 = 0.f, pc1 = 0.f, pc2 = 0.f;
#pragma unroll
      for (int r = 0; r < 4; ++r) {
        const float av0 = fmaxf(acc0[r] + dvv[0][r], 0.0f);
        const float av1 = fmaxf(acc1[r] + dvv[1][r], 0.0f);
        pc0 += av0 * w2v[0][r][0] + av1 * w2v[1][r][0];
        pc1 += av0 * w2v[0][r][1] + av1 * w2v[1][r][1];
        pc2 += av0 * w2v[0][r][2] + av1 * w2v[1][r][2];
      }
      // reduce over the 4 quads
#pragma unroll
      for (int mask = 16; mask < 64; mask <<= 1) {
        pc0 += __shfl_xor(pc0, mask, 64);
        pc1 += __shfl_xor(pc1, mask, 64);
        pc2 += __shfl_xor(pc2, mask, 64);
      }
      const int cidx = lane >> 4;
      const float oc = (cidx == 0) ? pc0 : ((cidx == 1) ? pc1 : pc2);
      if (lane < 48) {
        const int s = sbase + (lane & 15);
        const float o = oc + sw[BC2 + cidx];
        s_rgb[s * RGBS + cidx] = fast_rcp(1.0f + __expf(-o));
      }
    }
  }

  // ---- fine alpha + parallel cumprod over 128 ----
  const float deltaf = (t < SF - 1) ? (s_zlf[t + 1] - zlf) : 0.0f;
  const float vf = __expf(-sigf * deltaf);
  const float af = 1.0f - vf;
  float fi = wave_scan_mul(vf, lane);
  if (lane == 63) s_tot[wv] = fi;
  __syncthreads();   // also makes s_rgb visible
  float efx = __shfl_up(fi, 1, 64); if (lane == 0) efx = 1.0f;
  const float wf = af * efx * (wv ? s_tot[0] : 1.0f);

  // ---- outputs ----
  float* o_img = out;
  float* o_w   = out + (size_t)n_rays * 3;
  float* o_z   = out + (size_t)n_rays * (3 + 128);
  float* o_inv = out + (size_t)n_rays * (3 + 256);

  o_w[(size_t)ray * 128 + t] = wf;
  o_z[(size_t)ray * 128 + t] = (zlf + 1.0f) * 0.5f;

  float r0 = wf * s_rgb[t * RGBS + 0];
  float r1 = wf * s_rgb[t * RGBS + 1];
  float r2 = wf * s_rgb[t * RGBS + 2];
  float r3 = wf, r4 = wf * fast_rcp(zf);
#pragma unroll
  for (int d = 32; d > 0; d >>= 1) {
    r0 += __shfl_down(r0, d, 64);
    r1 += __shfl_down(r1, d, 64);
    r2 += __shfl_down(r2, d, 64);
    r3 += __shfl_down(r3, d, 64);
    r4 += __shfl_down(r4, d, 64);
  }
  if (lane == 0) {
    float* p = &s_red[wv * 5];
    p[0] = r0; p[1] = r1; p[2] = r2; p[3] = r3; p[4] = r4;
  }
  __syncthreads();
  if (t == 0) {
    const float accw = s_red[3] + s_red[8];
    const float bgw = 1.0f - accw;
    o_img[(size_t)ray * 3 + 0] = (s_red[0] + s_red[5]) + bgw * bg[0];
    o_img[(size_t)ray * 3 + 1] = (s_red[1] + s_red[6]) + bgw * bg[1];
    o_img[(size_t)ray * 3 + 2] = (s_red[2] + s_red[7]) + bgw * bg[2];
    o_inv[ray] = s_red[4] + s_red[9];
  }
}

extern "C" void kernel_launch(void* const* d_in, const int* in_sizes, int n_in,
                              void* d_out, int out_size, void* d_ws, size_t ws_size,
                              hipStream_t stream) {
  const float* h   = (const float*)d_in[1];
  const float* w   = (const float*)d_in[2];
  const float* K   = (const float*)d_in[3];
  const float* E   = (const float*)d_in[4];
  const float* bg  = (const float*)d_in[5];
  const float* Wd1 = (const float*)d_in[6];
  const float* bd1 = (const float*)d_in[7];
  const float* Wd2 = (const float*)d_in[8];
  const float* bd2 = (const float*)d_in[9];
  const float* Wc1 = (const float*)d_in[10];
  const float* bc1 = (const float*)d_in[11];
  const float* Wc2 = (const float*)d_in[12];
  const float* bc2 = (const float*)d_in[13];
  const int n_rays = in_sizes[1];
  float* wsf = (float*)d_ws;

  if (ws_size >= WS_NEED) {
    pack_weights<<<1, NT, 0, stream>>>(Wd1, bd1, Wd2, bd2, Wc1, bc1, Wc2, bc2, wsf);
    nerf_fwd<true><<<n_rays, NT, 0, stream>>>(h, w, K, E, bg, Wd1, bd1, Wd2, bd2,
                                              Wc1, bc1, Wc2, bc2, wsf,
                                              (float*)d_out, n_rays);
  } else {
    nerf_fwd<false><<<n_rays, NT, 0, stream>>>(h, w, K, E, bg, Wd1, bd1, Wd2, bd2,
                                               Wc1, bc1, Wc2, bc2, nullptr,
                                               (float*)d_out, n_rays);
  }
}

// Round 13
// 167.084 us; speedup vs baseline: 24.4659x; 1.0782x over previous
//
#include <hip/hip_runtime.h>
#include <stdint.h>

#define SC 192      // coarse samples (128 + 64)
#define SF 128      // fine (importance) samples
#define NT 128      // threads per block = 2 waves

// LDS weight-image offsets (floats)
#define WD1   0     // 96  (3x32 row-major)
#define BD1   96    // 32
#define WD2   128   // 32
#define BD2   160   // 1
#define BC2   161   // 3
#define NV4   164   // 32 x float4: (bc1[n], Wc1[32][n], Wc1[33][n], Wc1[34][n])
#define W24   292   // 32 x float4: (Wc2[n][0],[1],[2], 0)
#define SWTOT 420   // floats (105 float4s)

#define WS_FRAG_OFF 2048    // byte offset of Wc1 fp16 A-frags in d_ws
#define WS_NEED     4096

#define HSTRIDE 40  // ushort stride for H rows (80 B rows -> bank-friendly)
#define RGBS 4

using half8 = __attribute__((ext_vector_type(8))) _Float16;
using f32x4 = __attribute__((ext_vector_type(4))) float;

__device__ __forceinline__ float zlog_c(int t) {
  return (t < 128) ? (-1.0f + (float)t * 0.0078125f)
                   : ((float)(t - 128) * 0.015625f);
}
__device__ __forceinline__ float delta_c(int t) {
  if (t >= SC - 1) return 0.0f;
  return zlog_c(t + 1) - zlog_c(t);
}

__device__ __forceinline__ float fast_rcp(float x) { return __builtin_amdgcn_rcpf(x); }
__device__ __forceinline__ float fast_rsq(float x) { return __builtin_amdgcn_rsqf(x); }
__device__ __forceinline__ float exp10_f(float x) { return __expf(x * 2.30258509299f); }
__device__ __forceinline__ float softplus_f(float x) {
  return fmaxf(x, 0.0f) + __logf(1.0f + __expf(-fabsf(x)));
}

// fp16 helpers: pk2h = 1 HW instr (v_cvt_pkrtz_f16_f32); f2h = RTN scalar convert
__device__ __forceinline__ uint32_t pk2h(float a, float b) {
  auto p = __builtin_amdgcn_cvt_pkrtz(a, b);
  uint32_t u; __builtin_memcpy(&u, &p, 4); return u;
}
__device__ __forceinline__ unsigned short f2h(float f) {
  _Float16 h = (_Float16)f;
  unsigned short us; __builtin_memcpy(&us, &h, 2); return us;
}

__device__ __forceinline__ float4 ldsf4(const float* p) { return *(const float4*)p; }

// JAX threefry2x32 with key = (0, 42)
__device__ __forceinline__ void threefry2x32_k42(uint32_t& x0, uint32_t& x1) {
  const uint32_t ks0 = 0u, ks1 = 42u;
  const uint32_t ks2 = ks0 ^ ks1 ^ 0x1BD11BDAu;
  const uint32_t ks[3] = {ks0, ks1, ks2};
  const int rot[2][4] = {{13, 15, 26, 6}, {17, 29, 16, 24}};
  x0 += ks[0];
  x1 += ks[1];
#pragma unroll
  for (int i = 0; i < 5; ++i) {
#pragma unroll
    for (int j = 0; j < 4; ++j) {
      x0 += x1;
      const int r = rot[i & 1][j];
      x1 = (x1 << r) | (x1 >> (32 - r));
      x1 ^= x0;
    }
    x0 += ks[(i + 1) % 3];
    x1 += ks[(i + 2) % 3] + (uint32_t)(i + 1);
  }
}

__device__ __forceinline__ float wave_scan_mul(float v, int lane) {
#pragma unroll
  for (int d = 1; d < 64; d <<= 1) {
    float o = __shfl_up(v, d, 64);
    if (lane >= d) v *= o;
  }
  return v;
}
__device__ __forceinline__ float wave_scan_add(float v, int lane) {
#pragma unroll
  for (int d = 1; d < 64; d <<= 1) {
    float o = __shfl_up(v, d, 64);
    if (lane >= d) v += o;
  }
  return v;
}

// ---- pre-pack kernel: weight image + fp16 Wc1 A-frags (identical for all blocks) ----
__global__ __launch_bounds__(NT) void pack_weights(
    const float* __restrict__ Wd1, const float* __restrict__ bd1,
    const float* __restrict__ Wd2, const float* __restrict__ bd2,
    const float* __restrict__ Wc1, const float* __restrict__ bc1,
    const float* __restrict__ Wc2, const float* __restrict__ bc2,
    float* __restrict__ wsf) {
  const int t = threadIdx.x;
  for (int i = t; i < 96; i += NT) wsf[WD1 + i] = Wd1[i];
  for (int i = t; i < 32; i += NT) { wsf[BD1 + i] = bd1[i]; wsf[WD2 + i] = Wd2[i]; }
  if (t == 0) {
    wsf[BD2] = bd2[0];
    wsf[BC2 + 0] = bc2[0]; wsf[BC2 + 1] = bc2[1]; wsf[BC2 + 2] = bc2[2];
  }
  if (t < 32) {
    wsf[NV4 + t * 4 + 0] = bc1[t];
    wsf[NV4 + t * 4 + 1] = Wc1[32 * 32 + t];
    wsf[NV4 + t * 4 + 2] = Wc1[33 * 32 + t];
    wsf[NV4 + t * 4 + 3] = Wc1[34 * 32 + t];
    wsf[W24 + t * 4 + 0] = Wc2[t * 3 + 0];
    wsf[W24 + t * 4 + 1] = Wc2[t * 3 + 1];
    wsf[W24 + t * 4 + 2] = Wc2[t * 3 + 2];
    wsf[W24 + t * 4 + 3] = 0.0f;
  }
  // Wc1[0:32][:] fp16 A-frags: frag[lane*2 + nt]; A[m=n][k], lane: n=nt*16+(lane&15), k=quad*8+j
  if (t < 64) {
    const int q_s = t >> 4;
    uint4* frag = (uint4*)((char*)wsf + WS_FRAG_OFF);
#pragma unroll
    for (int nt = 0; nt < 2; ++nt) {
      const int n_s = nt * 16 + (t & 15);
      uint32_t hw[4];
#pragma unroll
      for (int j2 = 0; j2 < 4; ++j2) {
        const int k = q_s * 8 + j2 * 2;
        hw[j2] = (uint32_t)f2h(Wc1[k * 32 + n_s])
               | ((uint32_t)f2h(Wc1[(k + 1) * 32 + n_s]) << 16);
      }
      frag[t * 2 + nt] = make_uint4(hw[0], hw[1], hw[2], hw[3]);
    }
  }
}

template <bool USE_WS>
__global__ __launch_bounds__(NT) void nerf_fwd(
    const float* __restrict__ hh, const float* __restrict__ ww,
    const float* __restrict__ K, const float* __restrict__ E,
    const float* __restrict__ bg,
    const float* __restrict__ Wd1, const float* __restrict__ bd1,
    const float* __restrict__ Wd2, const float* __restrict__ bd2,
    const float* __restrict__ Wc1, const float* __restrict__ bc1,
    const float* __restrict__ Wc2, const float* __restrict__ bc2,
    const float* __restrict__ wsf,
    float* __restrict__ out, int n_rays) {
  const int ray = blockIdx.x;
  const int t = threadIdx.x;
  const int lane = t & 63;
  const int wv = t >> 6;   // 0 or 1
  const int quad = lane >> 4;

  __shared__ __align__(16) float sw[SWTOT];
  // phase-union: coarse {s_w, s_cdf} then fine H (fp16)
  __shared__ __align__(16) unsigned char u_buf[SF * HSTRIDE * 2];  // 10240 B
  float* const s_w   = (float*)u_buf;
  float* const s_cdf = (float*)(u_buf + 768);
  unsigned short* const s_hf = (unsigned short*)u_buf;
  __shared__ float s_rgb[SF * RGBS];
  __shared__ float s_zlf[SF];
  __shared__ float s_tot[8];
  __shared__ float s_red[16];

  // ---- stage weight image into LDS ----
  if constexpr (USE_WS) {
    const float4* wsrc = (const float4*)wsf;
    float4* sdst = (float4*)sw;
    for (int i = t; i < SWTOT / 4; i += NT) sdst[i] = wsrc[i];
  } else {
    for (int i = t; i < 96; i += NT) sw[WD1 + i] = Wd1[i];
    for (int i = t; i < 32; i += NT) { sw[BD1 + i] = bd1[i]; sw[WD2 + i] = Wd2[i]; }
    if (t == 0) {
      sw[BD2] = bd2[0];
      sw[BC2 + 0] = bc2[0]; sw[BC2 + 1] = bc2[1]; sw[BC2 + 2] = bc2[2];
    }
    if (t < 32) {
      sw[NV4 + t * 4 + 0] = bc1[t];
      sw[NV4 + t * 4 + 1] = Wc1[32 * 32 + t];
      sw[NV4 + t * 4 + 2] = Wc1[33 * 32 + t];
      sw[NV4 + t * 4 + 3] = Wc1[34 * 32 + t];
      sw[W24 + t * 4 + 0] = Wc2[t * 3 + 0];
      sw[W24 + t * 4 + 1] = Wc2[t * 3 + 1];
      sw[W24 + t * 4 + 2] = Wc2[t * 3 + 2];
      sw[W24 + t * 4 + 3] = 0.0f;
    }
  }

  // ---- ray setup (block-uniform) ----
  const float k00 = K[0], k01 = K[1], k02 = K[2];
  const float k10 = K[3], k11 = K[4], k12 = K[5];
  const float k20 = K[6], k21 = K[7], k22 = K[8];
  const float det = k00 * (k11 * k22 - k12 * k21)
                  - k01 * (k10 * k22 - k12 * k20)
                  + k02 * (k10 * k21 - k11 * k20);
  const float id = 1.0f / det;
  const float i00 =  (k11 * k22 - k12 * k21) * id;
  const float i01 = -(k01 * k22 - k02 * k21) * id;
  const float i02 =  (k01 * k12 - k02 * k11) * id;
  const float i10 = -(k10 * k22 - k12 * k20) * id;
  const float i11 =  (k00 * k22 - k02 * k20) * id;
  const float i12 = -(k00 * k12 - k02 * k10) * id;
  const float i20 =  (k10 * k21 - k11 * k20) * id;
  const float i21 = -(k00 * k21 - k01 * k20) * id;
  const float i22 =  (k00 * k11 - k01 * k10) * id;

  const float dwx = ww[ray] + 0.5f;
  const float dwy = hh[ray] + 0.5f;
  const float cx = i00 * dwx + i01 * dwy + i02;
  const float cy = i10 * dwx + i11 * dwy + i12;
  const float cz = i20 * dwx + i21 * dwy + i22;
  const float* Er = E + (size_t)ray * 16;
  const float ox = Er[3], oy = Er[7], oz = Er[11];
  const float dx = Er[0] * cx + Er[1] * cy + Er[2] * cz;
  const float dy = Er[4] * cx + Er[5] * cy + Er[6] * cz;
  const float dz = Er[8] * cx + Er[9] * cy + Er[10] * cz;
  const float inv_nrm = fast_rsq(dx * dx + dy * dy + dz * dz);
  const float ndx = dx * inv_nrm, ndy = dy * inv_nrm, ndz = dz * inv_nrm;

  __syncthreads();   // weights staged

  // ---- coarse pass: e0 = t (all threads); e1 = 128+t (wave 0 only, FUSED loop) ----
  const float bd2v = sw[BD2];
  float a0, v0, a1e = 0.0f, v1e = 1.0f;
  {
    float px0, py0, pz0, px1 = 0.f, py1 = 0.f, pz1 = 0.f;
    {
      const float z = exp10_f(zlog_c(t));
      px0 = ox + dx * z; py0 = oy + dy * z; pz0 = oz + dz * z;
      const float dist = sqrtf(px0 * px0 + py0 * py0 + pz0 * pz0);
      if (dist > 1.0f) {
        const float invd = fast_rcp(dist);
        const float sc = (2.0f - invd) * invd;
        px0 *= sc; py0 *= sc; pz0 *= sc;
      }
    }
    if (wv == 0) {
      const float z = exp10_f((float)t * 0.015625f);   // zlog_c(128+t)
      px1 = ox + dx * z; py1 = oy + dy * z; pz1 = oz + dz * z;
      const float dist = sqrtf(px1 * px1 + py1 * py1 + pz1 * pz1);
      if (dist > 1.0f) {
        const float invd = fast_rcp(dist);
        const float sc = (2.0f - invd) * invd;
        px1 *= sc; py1 *= sc; pz1 *= sc;
      }
    }
    float acc0 = bd2v, acc1 = bd2v;
    if (wv == 0) {  // wave-uniform branch: fused 2-sample loop (weights loaded once)
#pragma unroll 2
      for (int c = 0; c < 8; ++c) {
        const int k4 = c * 4;
        const float4 w0 = ldsf4(sw + WD1 + k4);
        const float4 w1 = ldsf4(sw + WD1 + 32 + k4);
        const float4 w2 = ldsf4(sw + WD1 + 64 + k4);
        const float4 b  = ldsf4(sw + BD1 + k4);
        const float4 wd = ldsf4(sw + WD2 + k4);
        float v;
        v = b.x + px0 * w0.x + py0 * w1.x + pz0 * w2.x; acc0 += fmaxf(v, 0.0f) * wd.x;
        v = b.y + px0 * w0.y + py0 * w1.y + pz0 * w2.y; acc0 += fmaxf(v, 0.0f) * wd.y;
        v = b.z + px0 * w0.z + py0 * w1.z + pz0 * w2.z; acc0 += fmaxf(v, 0.0f) * wd.z;
        v = b.w + px0 * w0.w + py0 * w1.w + pz0 * w2.w; acc0 += fmaxf(v, 0.0f) * wd.w;
        v = b.x + px1 * w0.x + py1 * w1.x + pz1 * w2.x; acc1 += fmaxf(v, 0.0f) * wd.x;
        v = b.y + px1 * w0.y + py1 * w1.y + pz1 * w2.y; acc1 += fmaxf(v, 0.0f) * wd.y;
        v = b.z + px1 * w0.z + py1 * w1.z + pz1 * w2.z; acc1 += fmaxf(v, 0.0f) * wd.z;
        v = b.w + px1 * w0.w + py1 * w1.w + pz1 * w2.w; acc1 += fmaxf(v, 0.0f) * wd.w;
      }
    } else {
#pragma unroll 2
      for (int c = 0; c < 8; ++c) {
        const int k4 = c * 4;
        const float4 w0 = ldsf4(sw + WD1 + k4);
        const float4 w1 = ldsf4(sw + WD1 + 32 + k4);
        const float4 w2 = ldsf4(sw + WD1 + 64 + k4);
        const float4 b  = ldsf4(sw + BD1 + k4);
        const float4 wd = ldsf4(sw + WD2 + k4);
        float v;
        v = b.x + px0 * w0.x + py0 * w1.x + pz0 * w2.x; acc0 += fmaxf(v, 0.0f) * wd.x;
        v = b.y + px0 * w0.y + py0 * w1.y + pz0 * w2.y; acc0 += fmaxf(v, 0.0f) * wd.y;
        v = b.z + px0 * w0.z + py0 * w1.z + pz0 * w2.z; acc0 += fmaxf(v, 0.0f) * wd.z;
        v = b.w + px0 * w0.w + py0 * w1.w + pz0 * w2.w; acc0 += fmaxf(v, 0.0f) * wd.w;
      }
    }
    v0 = __expf(-softplus_f(acc0) * delta_c(t));
    a0 = 1.0f - v0;
    if (wv == 0) {
      v1e = __expf(-softplus_f(acc1) * delta_c(128 + t));
      a1e = 1.0f - v1e;
    }
  }

  // parallel cumprod of (1-alpha)
  float i0 = wave_scan_mul(v0, lane);
  float i1 = 1.0f;
  if (wv == 0) i1 = wave_scan_mul(v1e, lane);
  if (lane == 63) s_tot[wv] = i0;
  if (wv == 0 && lane == 63) s_tot[2] = i1;
  __syncthreads();
  {
    const float preC1 = s_tot[0];
    const float preC2 = s_tot[0] * s_tot[1];
    float e0x = __shfl_up(i0, 1, 64); if (lane == 0) e0x = 1.0f;
    s_w[t] = a0 * e0x * (wv ? preC1 : 1.0f);
    if (wv == 0) {
      float e1x = __shfl_up(i1, 1, 64); if (lane == 0) e1x = 1.0f;
      s_w[128 + t] = a1e * e1x * preC2;
    }
  }
  __syncthreads();

  // reweight
  float wre0, wre1 = 0.0f;
  {
    const float wm = (t > 0) ? s_w[t - 1] : 0.0f;
    const float w0 = s_w[t];
    const float wp = s_w[t + 1];
    wre0 = 0.5f * (fmaxf(wm, w0) + fmaxf(w0, wp)) + (0.02f / 192.0f);
    wre0 *= (t < 128) ? (128.0f / 192.0f) : (64.0f / 192.0f);
  }
  if (wv == 0) {
    const int e = 128 + t;
    const float wm = s_w[e - 1];
    const float w0 = s_w[e];
    const float wp = (e < SC - 1) ? s_w[e + 1] : 0.0f;
    wre1 = 0.5f * (fmaxf(wm, w0) + fmaxf(w0, wp)) + (0.02f / 192.0f);
    wre1 *= (64.0f / 192.0f);
  }

  // parallel cumsum -> normalized CDF
  float s0 = wave_scan_add(wre0, lane);
  float s1 = 0.0f;
  if (wv == 0) s1 = wave_scan_add(wre1, lane);
  if (lane == 63) s_tot[4 + wv] = s0;
  if (wv == 0 && lane == 63) s_tot[6] = s1;
  __syncthreads();
  {
    const float T0 = s_tot[4], T1 = s_tot[5], T2 = s_tot[6];
    const float inv_total = fast_rcp(T0 + T1 + T2);
    s_cdf[t] = (s0 + (wv ? T0 : 0.0f)) * inv_total;
    if (wv == 0) s_cdf[128 + t] = (s1 + T0 + T1) * inv_total;
  }
  __syncthreads();

  // ---- importance sampling ----
  float zlf, zf;
  {
    const uint32_t total = (uint32_t)n_rays * 128u;
    const uint32_t halfc = total >> 1;
    const uint32_t j = (uint32_t)ray * 128u + (uint32_t)t;
    uint32_t x0, x1;
    const bool first = (j < halfc);
    if (first) { x0 = j; x1 = j + halfc; } else { x0 = j - halfc; x1 = j; }
    threefry2x32_k42(x0, x1);
    const uint32_t bits = first ? x0 : x1;
    const float fr = __uint_as_float((bits >> 9) | 0x3f800000u) - 1.0f;

    float u = (float)t * 0.0078125f + fr * 0.0078125f;
    u = u * (s_cdf[190] - s_cdf[1]) + s_cdf[1];

    int lo = 0, hi = 189;
    while (lo < hi) {
      const int mid = (lo + hi) >> 1;
      if (s_cdf[1 + mid] <= u) lo = mid + 1; else hi = mid;
    }
    const int inds = lo + 1;
    const float cb = s_cdf[inds - 1], ca = s_cdf[inds];
    const float tt = (u - cb) * fast_rcp(ca - cb);
    const float zb = 0.5f * (zlog_c(inds - 1) + zlog_c(inds));
    const float za = 0.5f * (zlog_c(inds) + zlog_c(inds + 1));
    zlf = zb + (za - zb) * tt;
    s_zlf[t] = zlf;
    zf = exp10_f(zlf);
  }
  __syncthreads();   // last s_cdf read — union area now free for s_hf

  // ---- Wc1 A-frags (fp16, hi only) ----
  half8 Whi0, Whi1;
  if constexpr (USE_WS) {
    const uint4* frag = (const uint4*)((const char*)wsf + WS_FRAG_OFF);
    uint4 q0 = frag[lane * 2 + 0];
    uint4 q1 = frag[lane * 2 + 1];
    __builtin_memcpy(&Whi0, &q0, 16);
    __builtin_memcpy(&Whi1, &q1, 16);
  } else {
#pragma unroll
    for (int nt = 0; nt < 2; ++nt) {
      const int n_s = nt * 16 + (lane & 15);
      uint32_t hw[4];
#pragma unroll
      for (int j2 = 0; j2 < 4; ++j2) {
        const int k = quad * 8 + j2 * 2;
        hw[j2] = (uint32_t)f2h(Wc1[k * 32 + n_s])
               | ((uint32_t)f2h(Wc1[(k + 1) * 32 + n_s]) << 16);
      }
      uint4 q = make_uint4(hw[0], hw[1], hw[2], hw[3]);
      if (nt == 0) __builtin_memcpy(&Whi0, &q, 16);
      else         __builtin_memcpy(&Whi1, &q, 16);
    }
  }

  // ---- fine density per-thread; h -> LDS as fp16 (HW pack) ----
  float sigf;
  {
    float px = ox + dx * zf, py = oy + dy * zf, pz = oz + dz * zf;
    const float dist = sqrtf(px * px + py * py + pz * pz);
    if (dist > 1.0f) {
      const float invd = fast_rcp(dist);
      const float sc = (2.0f - invd) * invd;
      px *= sc; py *= sc; pz *= sc;
    }
    float sig_acc = bd2v;
    uint4 tmp;
#pragma unroll
    for (int c = 0; c < 8; ++c) {
      const int k4 = c * 4;
      const float4 w0 = ldsf4(sw + WD1 + k4);
      const float4 w1 = ldsf4(sw + WD1 + 32 + k4);
      const float4 w2 = ldsf4(sw + WD1 + 64 + k4);
      const float4 b  = ldsf4(sw + BD1 + k4);
      const float4 wd = ldsf4(sw + WD2 + k4);
      float h0 = fmaxf(b.x + px * w0.x + py * w1.x + pz * w2.x, 0.0f);
      float h1 = fmaxf(b.y + px * w0.y + py * w1.y + pz * w2.y, 0.0f);
      float h2 = fmaxf(b.z + px * w0.z + py * w1.z + pz * w2.z, 0.0f);
      float h3 = fmaxf(b.w + px * w0.w + py * w1.w + pz * w2.w, 0.0f);
      sig_acc += h0 * wd.x + h1 * wd.y + h2 * wd.z + h3 * wd.w;
      const uint32_t pA = pk2h(h0, h1), pB = pk2h(h2, h3);
      if ((c & 1) == 0) { tmp.x = pA; tmp.y = pB; }
      else {
        tmp.z = pA; tmp.w = pB;
        *(uint4*)(s_hf + t * HSTRIDE + (c >> 1) * 8) = tmp;
      }
    }
    sigf = softplus_f(sig_acc);
  }
  __syncthreads();   // h staged for MFMA

  // ---- fine color via MFMA: a1^T[32 x 128] = Wc1^T . H^T (fp16) ----
  {
    // per-lane n-values from packed NV4/W24 tables (b128 reads)
    float dvv[2][4], w2v[2][4][3];
#pragma unroll
    for (int nt = 0; nt < 2; ++nt)
#pragma unroll
      for (int r = 0; r < 4; ++r) {
        const int n = nt * 16 + quad * 4 + r;
        const float4 nv = ldsf4(sw + NV4 + n * 4);
        dvv[nt][r] = nv.x + ndx * nv.y + ndy * nv.z + ndz * nv.w;
        const float4 w2 = ldsf4(sw + W24 + n * 4);
        w2v[nt][r][0] = w2.x; w2v[nt][r][1] = w2.y; w2v[nt][r][2] = w2.z;
      }

#pragma unroll
    for (int mt = 0; mt < 4; ++mt) {
      const int sbase = wv * 64 + mt * 16;
      const int srow = sbase + (lane & 15);
      const half8 Hf = *(const half8*)(s_hf + srow * HSTRIDE + quad * 8);

      f32x4 acc0 = {0.f, 0.f, 0.f, 0.f}, acc1 = {0.f, 0.f, 0.f, 0.f};
      acc0 = __builtin_amdgcn_mfma_f32_16x16x32_f16(Whi0, Hf, acc0, 0, 0, 0);
      acc1 = __builtin_amdgcn_mfma_f32_16x16x32_f16(Whi1, Hf, acc1, 0, 0, 0);

      float pc0 = 0.f, pc1 = 0.f, pc2 = 0.f;
#pragma unroll
      for (int r = 0; r < 4; ++r) {
        const float av0 = fmaxf(acc0[r] + dvv[0][r], 0.0f);
        const float av1 = fmaxf(acc1[r] + dvv[1][r], 0.0f);
        pc0 += av0 * w2v[0][r][0] + av1 * w2v[1][r][0];
        pc1 += av0 * w2v[0][r][1] + av1 * w2v[1][r][1];
        pc2 += av0 * w2v[0][r][2] + av1 * w2v[1][r][2];
      }
#pragma unroll
      for (int mask = 16; mask < 64; mask <<= 1) {
        pc0 += __shfl_xor(pc0, mask, 64);
        pc1 += __shfl_xor(pc1, mask, 64);
        pc2 += __shfl_xor(pc2, mask, 64);
      }
      const int cidx = lane >> 4;
      const float oc = (cidx == 0) ? pc0 : ((cidx == 1) ? pc1 : pc2);
      if (lane < 48) {
        const int s = sbase + (lane & 15);
        const float o = oc + sw[BC2 + cidx];
        s_rgb[s * RGBS + cidx] = fast_rcp(1.0f + __expf(-o));
      }
    }
  }

  // ---- fine alpha + parallel cumprod over 128 ----
  const float deltaf = (t < SF - 1) ? (s_zlf[t + 1] - zlf) : 0.0f;
  const float vf = __expf(-sigf * deltaf);
  const float af = 1.0f - vf;
  float fi = wave_scan_mul(vf, lane);
  if (lane == 63) s_tot[wv] = fi;
  __syncthreads();   // also makes s_rgb visible
  float efx = __shfl_up(fi, 1, 64); if (lane == 0) efx = 1.0f;
  const float wf = af * efx * (wv ? s_tot[0] : 1.0f);

  // ---- outputs ----
  float* o_img = out;
  float* o_w   = out + (size_t)n_rays * 3;
  float* o_z   = out + (size_t)n_rays * (3 + 128);
  float* o_inv = out + (size_t)n_rays * (3 + 256);

  o_w[(size_t)ray * 128 + t] = wf;
  o_z[(size_t)ray * 128 + t] = (zlf + 1.0f) * 0.5f;

  float r0 = wf * s_rgb[t * RGBS + 0];
  float r1 = wf * s_rgb[t * RGBS + 1];
  float r2 = wf * s_rgb[t * RGBS + 2];
  float r3 = wf, r4 = wf * fast_rcp(zf);
#pragma unroll
  for (int d = 32; d > 0; d >>= 1) {
    r0 += __shfl_down(r0, d, 64);
    r1 += __shfl_down(r1, d, 64);
    r2 += __shfl_down(r2, d, 64);
    r3 += __shfl_down(r3, d, 64);
    r4 += __shfl_down(r4, d, 64);
  }
  if (lane == 0) {
    float* p = &s_red[wv * 5];
    p[0] = r0; p[1] = r1; p[2] = r2; p[3] = r3; p[4] = r4;
  }
  __syncthreads();
  if (t == 0) {
    const float accw = s_red[3] + s_red[8];
    const float bgw = 1.0f - accw;
    o_img[(size_t)ray * 3 + 0] = (s_red[0] + s_red[5]) + bgw * bg[0];
    o_img[(size_t)ray * 3 + 1] = (s_red[1] + s_red[6]) + bgw * bg[1];
    o_img[(size_t)ray * 3 + 2] = (s_red[2] + s_red[7]) + bgw * bg[2];
    o_inv[ray] = s_red[4] + s_red[9];
  }
}

extern "C" void kernel_launch(void* const* d_in, const int* in_sizes, int n_in,
                              void* d_out, int out_size, void* d_ws, size_t ws_size,
                              hipStream_t stream) {
  const float* h   = (const float*)d_in[1];
  const float* w   = (const float*)d_in[2];
  const float* K   = (const float*)d_in[3];
  const float* E   = (const float*)d_in[4];
  const float* bg  = (const float*)d_in[5];
  const float* Wd1 = (const float*)d_in[6];
  const float* bd1 = (const float*)d_in[7];
  const float* Wd2 = (const float*)d_in[8];
  const float* bd2 = (const float*)d_in[9];
  const float* Wc1 = (const float*)d_in[10];
  const float* bc1 = (const float*)d_in[11];
  const float* Wc2 = (const float*)d_in[12];
  const float* bc2 = (const float*)d_in[13];
  const int n_rays = in_sizes[1];
  float* wsf = (float*)d_ws;

  if (ws_size >= WS_NEED) {
    pack_weights<<<1, NT, 0, stream>>>(Wd1, bd1, Wd2, bd2, Wc1, bc1, Wc2, bc2, wsf);
    nerf_fwd<true><<<n_rays, NT, 0, stream>>>(h, w, K, E, bg, Wd1, bd1, Wd2, bd2,
                                              Wc1, bc1, Wc2, bc2, wsf,
                                              (float*)d_out, n_rays);
  } else {
    nerf_fwd<false><<<n_rays, NT, 0, stream>>>(h, w, K, E, bg, Wd1, bd1, Wd2, bd2,
                                               Wc1, bc1, Wc2, bc2, nullptr,
                                               (float*)d_out, n_rays);
  }
}